// Round 1
// baseline (10160.778 us; speedup 1.0000x reference)
//
#include <hip/hip_runtime.h>
#include <string.h>

// ---------------------------------------------------------------- types
typedef __bf16 bf16_t;
typedef bf16_t bf16x8 __attribute__((ext_vector_type(8)));
typedef bf16_t bf16x4 __attribute__((ext_vector_type(4)));
typedef float  f32x4  __attribute__((ext_vector_type(4)));

#define MFMA16(a,b,c) __builtin_amdgcn_mfma_f32_16x16x32_bf16((a),(b),(c),0,0,0)

// Problem dims
#define TSTEPS 64
#define NB     512
#define DIN    556
#define LDSK   40
#define GRIDP  256   // persistent grid: 256 blocks x 256 threads (1 block/CU)

// bf16 weight-pool element offsets
#define OFF_WIHP_L 0u
#define OFF_WHH_L  327680u
#define OFF_WIHP_A 589824u
#define OFF_WHH_A  655360u
#define OFF_WIHP_V 720896u
#define OFF_WHH_V  786432u
#define OFF_ATT1W1 851968u
#define OFF_ATT1W2 1376256u
#define OFF_ATT2W1 1900544u
#define OFF_ATT2W2 2424832u
#define OFF_G1W1   2555904u
#define OFF_G1W2   3211264u
#define OFF_G2W1   3342336u
#define OFF_G2W2   3997696u
#define OFF_FLW    4128768u
#define OFF_FAW    4161536u
#define OFF_FVW    4177920u

__device__ __forceinline__ float sigmoidf_(float x) {
  return 1.0f / (1.0f + __expf(-x));
}
__device__ __forceinline__ float tanhf_(float x) {
  x = fminf(fmaxf(x, -15.0f), 15.0f);
  float e = __expf(2.0f * x);
  return (e - 1.0f) / (e + 1.0f);
}

// ============================================================ PArgs
struct PArgs {
  const float* x;
  const float* bih_l; const float* bhh_l;
  const float* bih_a; const float* bhh_a;
  const float* bih_v; const float* bhh_v;
  const float* att1_b1; const float* att1_b2;
  const float* att2_b1; const float* att2_b2;
  const float* g1_b1; const float* g1_b2;
  const float* g2_b1; const float* g2_b2;
  const float* fl_b; const float* fa_b; const float* fv_b;
  const float* o_w1; const float* o_b1; const float* o_w2; const float* o_b2;
  // weight conversion table
  const float* cvt_src[17];
  unsigned cvt_dst[17];
  int cvt_K[17]; int cvt_Kpad[17]; int cvt_rows[17];
  // workspace
  bf16_t* POOL; bf16_t* XL; bf16_t* XA; bf16_t* XV;
  bf16_t* HB0; bf16_t* HB1; float* CBUF; float* MEMF; bf16_t* MEMBF;
  bf16_t* CSTAR; bf16_t* Z1; float* LOGB; bf16_t* ATTD; bf16_t* Z3;
  float* PL; float* MAXP; float* BSUM;
  unsigned* BAR;
  float* out;
};

// ============================================================ grid barrier
// Two-level: 8 group counters (64B apart) -> 1 root. Monotonic targets, no
// resets (BAR is memset to 0 before each kernel run). All blocks call gbar
// the same number of times with the same k.
__device__ __forceinline__ void gbar(unsigned* bar, unsigned k, int bid) {
  __syncthreads();
  if (threadIdx.x == 0) {
    __threadfence();   // agent-scope release (wb L2)
    unsigned* gc   = bar + (bid & 7) * 16;
    unsigned* root = bar + 128;
    if (__hip_atomic_fetch_add(gc, 1u, __ATOMIC_ACQ_REL, __HIP_MEMORY_SCOPE_AGENT)
        == 32u * (k + 1u) - 1u) {
      __hip_atomic_fetch_add(root, 1u, __ATOMIC_ACQ_REL, __HIP_MEMORY_SCOPE_AGENT);
    }
    while (__hip_atomic_load(root, __ATOMIC_RELAXED, __HIP_MEMORY_SCOPE_AGENT)
           < 8u * (k + 1u)) {
      __builtin_amdgcn_s_sleep(1);
    }
    __threadfence();   // agent-scope acquire (inv L2)
  }
  __syncthreads();
}

// ============================================================ phase bodies
// ---- gates + cell (job in [0,128): m-tile = job>>4, y = job&15)
__device__ __forceinline__ void gates_body(const PArgs& p, int job, int t, char* SM) {
  bf16_t* Al = (bf16_t*)SM;                         // 64*40*2   = 5120
  bf16_t* Wl = (bf16_t*)(SM + 5120);                // 128*40*2  = 10240
  float (*Gx)[64][32] = (float (*)[64][32])(SM + 15360); // 32768

  const int tid = threadIdx.x;
  const int m0 = (job >> 4) * 64;
  const int y  = job & 15;

  const bf16_t* hin = (t & 1) ? p.HB1 : p.HB0;
  bf16_t* hout      = (t & 1) ? p.HB0 : p.HB1;

  const bf16_t *xp, *Wih, *Whh;
  int Kx, Hm, hoff, j0, oldbase, boff;
  if (y < 8) {
    xp = p.XL + (size_t)t * NB * 320; Wih = p.POOL + OFF_WIHP_L; Whh = p.POOL + OFF_WHH_L;
    Kx = 320; Hm = 256; hoff = 0; j0 = y * 32; oldbase = 0; boff = 0;
  } else if (y < 12) {
    xp = p.XA + (size_t)t * NB * 128; Wih = p.POOL + OFF_WIHP_A; Whh = p.POOL + OFF_WHH_A;
    Kx = 128; Hm = 128; hoff = 131072; j0 = (y - 8) * 32; oldbase = 256; boff = 1024;
  } else {
    xp = p.XV + (size_t)t * NB * 128; Wih = p.POOL + OFF_WIHP_V; Whh = p.POOL + OFF_WHH_V;
    Kx = 128; Hm = 128; hoff = 196608; j0 = (y - 12) * 32; oldbase = 384; boff = 1536;
  }

  const int wave = tid >> 6, lane = tid & 63;
  const int lrow = lane & 15, quad = lane >> 4;
  const int srow = tid >> 2, schunk = (tid & 3) * 8;
  const int wrow = tid >> 1, wchunk = (tid & 1) * 16;

  f32x4 acc[4][2];
  #pragma unroll
  for (int mi = 0; mi < 4; mi++)
    #pragma unroll
    for (int ni = 0; ni < 2; ni++) acc[mi][ni] = f32x4{0.f, 0.f, 0.f, 0.f};

  for (int ph = 0; ph < 2; ph++) {
    const bf16_t* Ab; const bf16_t* Wb; int lda_, ldw_, K_;
    if (ph == 0) { Ab = xp;           lda_ = Kx; K_ = Kx; Wb = Wih; ldw_ = Kx; }
    else         { Ab = hin + hoff;   lda_ = Hm; K_ = Hm; Wb = Whh; ldw_ = Hm; }

    for (int k0 = 0; k0 < K_; k0 += 32) {
      bf16x8 av = *(const bf16x8*)(Ab + (size_t)(m0 + srow) * lda_ + k0 + schunk);
      int g = wrow >> 5, jr = wrow & 31;
      const bf16_t* wsrc = Wb + (size_t)(g * Hm + j0 + jr) * ldw_ + k0 + wchunk;
      bf16x8 wv0 = *(const bf16x8*)(wsrc);
      bf16x8 wv1 = *(const bf16x8*)(wsrc + 8);
      *(bf16x8*)(Al + srow * LDSK + schunk) = av;
      *(bf16x8*)(Wl + wrow * LDSK + wchunk) = wv0;
      *(bf16x8*)(Wl + wrow * LDSK + wchunk + 8) = wv1;
      __syncthreads();
      bf16x8 afr[4], bfr[2];
      #pragma unroll
      for (int mi = 0; mi < 4; mi++)
        afr[mi] = *(const bf16x8*)(Al + (mi * 16 + lrow) * LDSK + quad * 8);
      #pragma unroll
      for (int ni = 0; ni < 2; ni++)
        bfr[ni] = *(const bf16x8*)(Wl + (wave * 32 + ni * 16 + lrow) * LDSK + quad * 8);
      #pragma unroll
      for (int mi = 0; mi < 4; mi++)
        #pragma unroll
        for (int ni = 0; ni < 2; ni++)
          acc[mi][ni] = MFMA16(afr[mi], bfr[ni], acc[mi][ni]);
      __syncthreads();
    }
  }

  #pragma unroll
  for (int mi = 0; mi < 4; mi++)
    #pragma unroll
    for (int ni = 0; ni < 2; ni++) {
      int col = ni * 16 + lrow;
      float bv = p.BSUM[boff + wave * Hm + j0 + col];
      #pragma unroll
      for (int r = 0; r < 4; r++) {
        Gx[wave][mi * 16 + quad * 4 + r][col] = acc[mi][ni][r] + bv;
      }
    }
  __syncthreads();

  float* cbuf = p.CBUF + hoff;
  int m = tid >> 2, jb = (tid & 3) * 8;
  #pragma unroll
  for (int i = 0; i < 8; i++) {
    int j = jb + i;
    float gi = Gx[0][m][j], gf = Gx[1][m][j], gg = Gx[2][m][j], go = Gx[3][m][j];
    size_t off = (size_t)(m0 + m) * Hm + (j0 + j);
    float c_old = cbuf[off];
    float c2 = sigmoidf_(gf) * c_old + sigmoidf_(gi) * tanhf_(gg);
    float h2 = sigmoidf_(go) * tanhf_(c2);
    cbuf[off] = c2;
    hout[hoff + off] = (bf16_t)h2;
    size_t cs = (size_t)(m0 + m) * 1024 + oldbase + (j0 + j);
    p.CSTAR[cs] = (bf16_t)c_old;
    p.CSTAR[cs + 512] = (bf16_t)c2;
  }
  __syncthreads();
}

// ---- generic 64x64 lin tile: C = act(A @ W^T + b)
__device__ __forceinline__ void lin_body(
    const bf16_t* __restrict__ A, int lda,
    const bf16_t* __restrict__ W, int ldw,
    const float* __restrict__ bias,
    bf16_t* Cb, float* Cf, int ldc, int K, int act,
    int m0, int n0, char* SM)
{
  bf16_t* Al = (bf16_t*)SM;           // 5120
  bf16_t* Wl = (bf16_t*)(SM + 5120);  // 5120
  const int tid = threadIdx.x;
  const int wave = tid >> 6, lane = tid & 63;
  const int wm = (wave >> 1) * 32, wn = (wave & 1) * 32;
  const int lrow = lane & 15, quad = lane >> 4;
  const int srow = tid >> 2, schunk = (tid & 3) * 8;

  f32x4 acc[2][2];
  #pragma unroll
  for (int mi = 0; mi < 2; mi++)
    #pragma unroll
    for (int ni = 0; ni < 2; ni++) acc[mi][ni] = f32x4{0.f, 0.f, 0.f, 0.f};

  for (int k0 = 0; k0 < K; k0 += 32) {
    bf16x8 av = *(const bf16x8*)(A + (size_t)(m0 + srow) * lda + k0 + schunk);
    bf16x8 wv = *(const bf16x8*)(W + (size_t)(n0 + srow) * ldw + k0 + schunk);
    *(bf16x8*)(Al + srow * LDSK + schunk) = av;
    *(bf16x8*)(Wl + srow * LDSK + schunk) = wv;
    __syncthreads();
    bf16x8 a0 = *(const bf16x8*)(Al + (wm + lrow) * LDSK + quad * 8);
    bf16x8 a1 = *(const bf16x8*)(Al + (wm + 16 + lrow) * LDSK + quad * 8);
    bf16x8 b0 = *(const bf16x8*)(Wl + (wn + lrow) * LDSK + quad * 8);
    bf16x8 b1 = *(const bf16x8*)(Wl + (wn + 16 + lrow) * LDSK + quad * 8);
    acc[0][0] = MFMA16(a0, b0, acc[0][0]);
    acc[0][1] = MFMA16(a0, b1, acc[0][1]);
    acc[1][0] = MFMA16(a1, b0, acc[1][0]);
    acc[1][1] = MFMA16(a1, b1, acc[1][1]);
    __syncthreads();
  }
  #pragma unroll
  for (int mi = 0; mi < 2; mi++)
    #pragma unroll
    for (int ni = 0; ni < 2; ni++) {
      int row0 = m0 + wm + mi * 16 + quad * 4;
      int col = n0 + wn + ni * 16 + lrow;
      float bv = bias[col];
      #pragma unroll
      for (int r = 0; r < 4; r++) {
        float v = acc[mi][ni][r] + bv;
        if (act == 1) v = fmaxf(v, 0.f);
        size_t off = (size_t)(row0 + r) * ldc + col;
        if (Cb) Cb[off] = (bf16_t)v;
        if (Cf) Cf[off] = v;
      }
    }
}

// ---- softmax over 1024 + attended (job = row n)
__device__ __forceinline__ void softmax_body(const PArgs& p, int n, char* SM) {
  float* red = (float*)SM;
  const int tid = threadIdx.x;
  float4 v = *(const float4*)(p.LOGB + (size_t)n * 1024 + tid * 4);
  float mx = fmaxf(fmaxf(v.x, v.y), fmaxf(v.z, v.w));
  red[tid] = mx; __syncthreads();
  for (int s = 128; s > 0; s >>= 1) {
    if (tid < s) red[tid] = fmaxf(red[tid], red[tid + s]);
    __syncthreads();
  }
  mx = red[0]; __syncthreads();
  float e0 = __expf(v.x - mx), e1 = __expf(v.y - mx);
  float e2 = __expf(v.z - mx), e3 = __expf(v.w - mx);
  red[tid] = e0 + e1 + e2 + e3; __syncthreads();
  for (int s = 128; s > 0; s >>= 1) {
    if (tid < s) red[tid] += red[tid + s];
    __syncthreads();
  }
  float inv = 1.0f / red[0];
  bf16x4 c4 = *(const bf16x4*)(p.CSTAR + (size_t)n * 1024 + tid * 4);
  bf16x4 o;
  o[0] = (bf16_t)(e0 * inv * (float)c4[0]);
  o[1] = (bf16_t)(e1 * inv * (float)c4[1]);
  o[2] = (bf16_t)(e2 * inv * (float)c4[2]);
  o[3] = (bf16_t)(e3 * inv * (float)c4[3]);
  *(bf16x4*)(p.ATTD + (size_t)n * 1024 + tid * 4) = o;
  __syncthreads();   // red reuse guard (2 jobs/block)
}

// ---- merged z2|zg1|zg2 (job in [0,192): m=job&7, ny=job>>3)
__device__ __forceinline__ void z3_body(const PArgs& p, int job, char* SM) {
  bf16_t* Al = (bf16_t*)SM;
  bf16_t* Wl = (bf16_t*)(SM + 5120);
  const int tid = threadIdx.x;
  const int m0 = (job & 7) * 64, n0 = (job >> 3) * 64;
  const int wave = tid >> 6, lane = tid & 63;
  const int wm = (wave >> 1) * 32, wn = (wave & 1) * 32;
  const int lrow = lane & 15, quad = lane >> 4;
  const int srow = tid >> 2, schunk = (tid & 3) * 8;

  const bf16_t* W; const float* b; int K, nloc;
  if (n0 < 512)       { W = p.POOL + OFF_ATT2W1; b = p.att2_b1; K = 1024; nloc = n0; }
  else if (n0 < 1024) { W = p.POOL + OFF_G1W1;  b = p.g1_b1;  K = 1280; nloc = n0 - 512; }
  else                { W = p.POOL + OFF_G2W1;  b = p.g2_b1;  K = 1280; nloc = n0 - 1024; }

  f32x4 acc[2][2];
  #pragma unroll
  for (int mi = 0; mi < 2; mi++)
    #pragma unroll
    for (int ni = 0; ni < 2; ni++) acc[mi][ni] = f32x4{0.f, 0.f, 0.f, 0.f};

  for (int k0 = 0; k0 < K; k0 += 32) {
    bf16x8 av;
    if (k0 < 1024)
      av = *(const bf16x8*)(p.ATTD + (size_t)(m0 + srow) * 1024 + k0 + schunk);
    else
      av = *(const bf16x8*)(p.MEMBF + (size_t)(m0 + srow) * 256 + (k0 - 1024) + schunk);
    bf16x8 wv = *(const bf16x8*)(W + (size_t)(nloc + srow) * K + k0 + schunk);
    *(bf16x8*)(Al + srow * LDSK + schunk) = av;
    *(bf16x8*)(Wl + srow * LDSK + schunk) = wv;
    __syncthreads();
    bf16x8 a0 = *(const bf16x8*)(Al + (wm + lrow) * LDSK + quad * 8);
    bf16x8 a1 = *(const bf16x8*)(Al + (wm + 16 + lrow) * LDSK + quad * 8);
    bf16x8 b0 = *(const bf16x8*)(Wl + (wn + lrow) * LDSK + quad * 8);
    bf16x8 b1 = *(const bf16x8*)(Wl + (wn + 16 + lrow) * LDSK + quad * 8);
    acc[0][0] = MFMA16(a0, b0, acc[0][0]);
    acc[0][1] = MFMA16(a0, b1, acc[0][1]);
    acc[1][0] = MFMA16(a1, b0, acc[1][0]);
    acc[1][1] = MFMA16(a1, b1, acc[1][1]);
    __syncthreads();
  }
  #pragma unroll
  for (int mi = 0; mi < 2; mi++)
    #pragma unroll
    for (int ni = 0; ni < 2; ni++) {
      int row0 = m0 + wm + mi * 16 + quad * 4;
      int cloc = wn + ni * 16 + lrow;
      float bv = b[nloc + cloc];
      #pragma unroll
      for (int r = 0; r < 4; r++) {
        float v = fmaxf(acc[mi][ni][r] + bv, 0.f);
        p.Z3[(size_t)(row0 + r) * 1536 + n0 + cloc] = (bf16_t)v;
      }
    }
}

// ---- cHat/gamma1/gamma2 GEMMs + mem update (job in [0,32))
__device__ __forceinline__ void gmem_body(const PArgs& p, int job, char* SM) {
  const int tid = threadIdx.x;
  const int m0 = (job & 7) * 64, n0 = (job >> 3) * 64;
  const int wave = tid >> 6, lane = tid & 63;
  const int wm = (wave >> 1) * 32, wn = (wave & 1) * 32;
  const int lrow = lane & 15, quad = lane >> 4;
  const int srow = tid >> 2, schunk = (tid & 3) * 8;

  const bf16_t* Ws[3] = { p.POOL + OFF_ATT2W2, p.POOL + OFF_G1W2, p.POOL + OFF_G2W2 };

  f32x4 acc[3][2][2];
  #pragma unroll
  for (int s = 0; s < 3; s++)
    #pragma unroll
    for (int mi = 0; mi < 2; mi++)
      #pragma unroll
      for (int ni = 0; ni < 2; ni++) acc[s][mi][ni] = f32x4{0.f, 0.f, 0.f, 0.f};

  for (int k0 = 0; k0 < 512; k0 += 32) {
    #pragma unroll
    for (int s = 0; s < 3; s++) {
      bf16_t* Az = (bf16_t*)(SM + s * 5120);
      bf16_t* Wz = (bf16_t*)(SM + 15360 + s * 5120);
      bf16x8 av = *(const bf16x8*)(p.Z3 + (size_t)(m0 + srow) * 1536 + s * 512 + k0 + schunk);
      bf16x8 wv = *(const bf16x8*)(Ws[s] + (size_t)(n0 + srow) * 512 + k0 + schunk);
      *(bf16x8*)(Az + srow * LDSK + schunk) = av;
      *(bf16x8*)(Wz + srow * LDSK + schunk) = wv;
    }
    __syncthreads();
    #pragma unroll
    for (int s = 0; s < 3; s++) {
      bf16_t* Az = (bf16_t*)(SM + s * 5120);
      bf16_t* Wz = (bf16_t*)(SM + 15360 + s * 5120);
      bf16x8 a0 = *(const bf16x8*)(Az + (wm + lrow) * LDSK + quad * 8);
      bf16x8 a1 = *(const bf16x8*)(Az + (wm + 16 + lrow) * LDSK + quad * 8);
      bf16x8 b0 = *(const bf16x8*)(Wz + (wn + lrow) * LDSK + quad * 8);
      bf16x8 b1 = *(const bf16x8*)(Wz + (wn + 16 + lrow) * LDSK + quad * 8);
      acc[s][0][0] = MFMA16(a0, b0, acc[s][0][0]);
      acc[s][0][1] = MFMA16(a0, b1, acc[s][0][1]);
      acc[s][1][0] = MFMA16(a1, b0, acc[s][1][0]);
      acc[s][1][1] = MFMA16(a1, b1, acc[s][1][1]);
    }
    __syncthreads();
  }
  #pragma unroll
  for (int mi = 0; mi < 2; mi++)
    #pragma unroll
    for (int ni = 0; ni < 2; ni++) {
      int row0 = m0 + wm + mi * 16 + quad * 4;
      int col = n0 + wn + ni * 16 + lrow;
      float bC = p.att2_b2[col], b1v = p.g1_b2[col], b2v = p.g2_b2[col];
      #pragma unroll
      for (int r = 0; r < 4; r++) {
        float cHat = tanhf_(acc[0][mi][ni][r] + bC);
        float g1 = sigmoidf_(acc[1][mi][ni][r] + b1v);
        float g2 = sigmoidf_(acc[2][mi][ni][r] + b2v);
        size_t off = (size_t)(row0 + r) * 256 + col;
        float nm = g1 * p.MEMF[off] + g2 * cHat;
        p.MEMF[off] = nm;
        p.MEMBF[off] = (bf16_t)nm;
      }
    }
}

// ---- partial max (job in [0,48): b=job>>4, chunk=job&15 covers 32 rows)
__device__ __forceinline__ void maxpart_body(const PArgs& p, int job, char* SM) {
  float* red = (float*)SM;
  const int b = job >> 4, chunk = job & 15;
  const int tid = threadIdx.x;
  float mx = -3.4e38f;
  for (int i = tid; i < 32 * 128; i += 256) {
    int n = chunk * 32 + (i >> 7), j = i & 127;
    mx = fmaxf(mx, p.PL[(size_t)n * 384 + b * 128 + j]);
  }
  red[tid] = mx; __syncthreads();
  for (int s = 128; s > 0; s >>= 1) {
    if (tid < s) red[tid] = fmaxf(red[tid], red[tid + s]);
    __syncthreads();
  }
  if (tid == 0) p.MAXP[job] = red[0];
  __syncthreads();
}

// ---- final output row (job = row n)
__device__ __forceinline__ void out_body(const PArgs& p, int n, char* SM) {
  float* hs  = (float*)SM;          // 384 floats
  float* red = (float*)(SM + 1536); // 256 floats
  float* Ms  = (float*)(SM + 2560); // 3 floats
  const int tid = threadIdx.x;
  if (tid < 3) {
    float m = -3.4e38f;
    #pragma unroll
    for (int i = 0; i < 16; i++) m = fmaxf(m, p.MAXP[tid * 16 + i]);
    Ms[tid] = m;
  }
  __syncthreads();
  const float M0 = Ms[0], M1 = Ms[1], M2 = Ms[2];
  for (int idx = tid; idx < 384; idx += 256) {
    float v;
    if (idx < 128) {
      float d0 = p.PL[(size_t)n * 384 + idx] - M0;
      float d1 = p.PL[(size_t)n * 384 + 128 + idx] - M1;
      float d2 = p.PL[(size_t)n * 384 + 256 + idx] - M2;
      v = __expf(d0) * d0 + __expf(d1) * d1 + __expf(d2) * d2;
    } else {
      v = p.MEMF[(size_t)n * 256 + idx - 128];
    }
    hs[idx] = v;
  }
  __syncthreads();
  float acc = p.o_b1[tid];
  const float* wr = p.o_w1 + (size_t)tid * 384;
  #pragma unroll 4
  for (int k = 0; k < 384; k += 4) {
    float4 w = *(const float4*)(wr + k);
    acc += w.x * hs[k] + w.y * hs[k + 1] + w.z * hs[k + 2] + w.w * hs[k + 3];
  }
  red[tid] = fmaxf(acc, 0.f) * p.o_w2[tid];
  __syncthreads();
  for (int s = 128; s > 0; s >>= 1) {
    if (tid < s) red[tid] += red[tid + s];
    __syncthreads();
  }
  if (tid == 0) p.out[n] = red[0] + p.o_b2[0];
  __syncthreads();  // hs/red reuse guard (2 jobs/block)
}

// ============================================================ persistent
__global__ void __launch_bounds__(256) persist_kernel(PArgs p) {
  __shared__ __align__(16) char SM[48640];
  const int bid = blockIdx.x;
  const int tid = threadIdx.x;
  unsigned bk = 0;

  // ---------------- P0: zero state + convert inputs/weights + bias sums
  {
    float4* z = (float4*)p.HB0;   // HB0,HB1,CBUF,MEMF,MEMBF contiguous
    for (int i = bid * 256 + tid; i < 180224; i += GRIDP * 256)
      z[i] = make_float4(0.f, 0.f, 0.f, 0.f);

    int gid = bid * 256 + tid;
    if (gid < 1024)      p.BSUM[gid] = p.bih_l[gid] + p.bhh_l[gid];
    else if (gid < 1536) p.BSUM[gid] = p.bih_a[gid - 1024] + p.bhh_a[gid - 1024];
    else if (gid < 2048) p.BSUM[gid] = p.bih_v[gid - 1536] + p.bhh_v[gid - 1536];

    // x split/convert: 1 float4 quad per thread per row
    for (int r = bid; r < TSTEPS * NB; r += GRIDP) {
      const float4* xr = (const float4*)(p.x + (size_t)r * DIN);
      int q = tid;
      if (q < 144) {
        float4 v; bf16_t* dst;
        if (q < 80) {
          v = (q < 75) ? xr[q] : make_float4(0.f, 0.f, 0.f, 0.f);
          dst = p.XL + (size_t)r * 320 + q * 4;
        } else if (q < 112) {
          v = xr[75 + (q - 80)];
          dst = p.XA + (size_t)r * 128 + (q - 80) * 4;
        } else {
          v = xr[107 + (q - 112)];
          dst = p.XV + (size_t)r * 128 + (q - 112) * 4;
        }
        bf16x4 o;
        o[0] = (bf16_t)v.x; o[1] = (bf16_t)v.y; o[2] = (bf16_t)v.z; o[3] = (bf16_t)v.w;
        *(bf16x4*)dst = o;
      }
    }

    // weight convert+pad (float4 vectorized; all K are multiples of 4)
    for (int m = 0; m < 17; m++) {
      const float* src = p.cvt_src[m];
      bf16_t* dst = p.POOL + p.cvt_dst[m];
      int K = p.cvt_K[m], Kp = p.cvt_Kpad[m], R = p.cvt_rows[m];
      int Kq = Kp >> 2, Ksq = K >> 2;
      for (int r = bid; r < R; r += GRIDP) {
        const float4* sr = (const float4*)(src + (size_t)r * K);
        for (int q = tid; q < Kq; q += 256) {
          float4 v = (q < Ksq) ? sr[q] : make_float4(0.f, 0.f, 0.f, 0.f);
          bf16x4 o;
          o[0] = (bf16_t)v.x; o[1] = (bf16_t)v.y; o[2] = (bf16_t)v.z; o[3] = (bf16_t)v.w;
          *(bf16x4*)(dst + (size_t)r * Kp + q * 4) = o;
        }
      }
    }
  }
  gbar(p.BAR, bk++, bid);

  // ---------------- recurrent loop: 5 grid syncs per step
  for (int t = 0; t < TSTEPS; t++) {
    for (int job = bid; job < 128; job += GRIDP) gates_body(p, job, t, SM);
    gbar(p.BAR, bk++, bid);

    for (int job = bid; job < 64; job += GRIDP)
      lin_body(p.CSTAR, 1024, p.POOL + OFF_ATT1W1, 1024, p.att1_b1,
               p.Z1, (float*)0, 512, 1024, 1, (job & 7) * 64, (job >> 3) * 64, SM);
    gbar(p.BAR, bk++, bid);

    for (int job = bid; job < 128; job += GRIDP)
      lin_body(p.Z1, 512, p.POOL + OFF_ATT1W2, 512, p.att1_b2,
               (bf16_t*)0, p.LOGB, 1024, 512, 0, (job & 7) * 64, (job >> 3) * 64, SM);
    gbar(p.BAR, bk++, bid);

    for (int job = bid; job < 512; job += GRIDP) softmax_body(p, job, SM);
    gbar(p.BAR, bk++, bid);

    for (int job = bid; job < 192; job += GRIDP) z3_body(p, job, SM);
    gbar(p.BAR, bk++, bid);

    for (int job = bid; job < 32; job += GRIDP) gmem_body(p, job, SM);
    // no barrier: gmem(t) only overlaps gates(t+1), which touches disjoint
    // buffers (hout/CBUF/CSTAR vs Z3/MEMF/MEMBF); the gates barrier orders
    // gmem(t) before z1(t+1) and z3(t+1).
  }
  gbar(p.BAR, bk++, bid);

  // ---------------- tail: PL GEMMs -> partial max -> output MLP
  for (int job = bid; job < 48; job += GRIDP) {
    int mat = job >> 4, rem = job & 15;
    int m0 = (rem & 7) * 64, n0 = (rem >> 3) * 64;
    const bf16_t* h = (mat == 0) ? p.HB0 : (mat == 1) ? p.HB0 + 131072 : p.HB0 + 196608;
    int lda = (mat == 0) ? 256 : 128;
    const bf16_t* W = p.POOL + ((mat == 0) ? OFF_FLW : (mat == 1) ? OFF_FAW : OFF_FVW);
    const float* b = (mat == 0) ? p.fl_b : (mat == 1) ? p.fa_b : p.fv_b;
    lin_body(h, lda, W, lda, b, (bf16_t*)0, p.PL + mat * 128, 384, lda, 0, m0, n0, SM);
  }
  gbar(p.BAR, bk++, bid);

  for (int job = bid; job < 48; job += GRIDP) maxpart_body(p, job, SM);
  gbar(p.BAR, bk++, bid);

  for (int job = bid; job < 512; job += GRIDP) out_body(p, job, SM);
}

// ============================================================ fallback path
// (original multi-kernel implementation, used only if the cooperative
//  launch is rejected)

__global__ __launch_bounds__(256) void zero_kernel(float4* p, int n4) {
  int i = blockIdx.x * 256 + threadIdx.x;
  if (i < n4) p[i] = make_float4(0.f, 0.f, 0.f, 0.f);
}

__global__ __launch_bounds__(256) void cvt_pad_kernel(
    const float* __restrict__ src, bf16_t* __restrict__ dst, int K, int Kpad)
{
  int r = blockIdx.x;
  for (int k = threadIdx.x; k < Kpad; k += 256)
    dst[(size_t)r * Kpad + k] = (k < K) ? (bf16_t)src[(size_t)r * K + k] : (bf16_t)0.f;
}

__global__ __launch_bounds__(256) void cvt_x_kernel(
    const float* __restrict__ x, bf16_t* __restrict__ xl,
    bf16_t* __restrict__ xa, bf16_t* __restrict__ xv)
{
  int r = blockIdx.x;
  const float* xr = x + (size_t)r * DIN;
  for (int c = threadIdx.x; c < 576; c += 256) {
    if (c < 320) {
      xl[(size_t)r * 320 + c] = (c < 300) ? (bf16_t)xr[c] : (bf16_t)0.f;
    } else if (c < 448) {
      xa[(size_t)r * 128 + (c - 320)] = (bf16_t)xr[300 + (c - 320)];
    } else {
      xv[(size_t)r * 128 + (c - 448)] = (bf16_t)xr[428 + (c - 448)];
    }
  }
}

__global__ __launch_bounds__(256) void bias_sum_kernel(
    const float* __restrict__ bih_l, const float* __restrict__ bhh_l,
    const float* __restrict__ bih_a, const float* __restrict__ bhh_a,
    const float* __restrict__ bih_v, const float* __restrict__ bhh_v,
    float* __restrict__ bsum)
{
  int i = blockIdx.x * 256 + threadIdx.x;
  if (i < 1024)      bsum[i] = bih_l[i] + bhh_l[i];
  else if (i < 1536) bsum[i] = bih_a[i - 1024] + bhh_a[i - 1024];
  else if (i < 2048) bsum[i] = bih_v[i - 1536] + bhh_v[i - 1536];
}

__global__ __launch_bounds__(256) void gates_cell_kernel_fb(
    PArgs p, int t)
{
  __shared__ __align__(16) char SM[48640];
  gates_body(p, blockIdx.x * 16 + blockIdx.y, t, SM);
}

__global__ __launch_bounds__(256) void mfma_lin_kernel_fb(
    const bf16_t* A, int lda, const bf16_t* W, int ldw,
    const float* bias, bf16_t* Cb, float* Cf, int ldc, int K, int act)
{
  __shared__ __align__(16) char SM[10240];
  lin_body(A, lda, W, ldw, bias, Cb, Cf, ldc, K, act,
           blockIdx.x * 64, blockIdx.y * 64, SM);
}

__global__ __launch_bounds__(256) void softmax_attend_kernel_fb(PArgs p) {
  __shared__ __align__(16) char SM[1024];
  softmax_body(p, blockIdx.x, SM);
}

__global__ __launch_bounds__(256) void z3_kernel_fb(PArgs p) {
  __shared__ __align__(16) char SM[10240];
  z3_body(p, blockIdx.x + blockIdx.y * 8, SM);
}

__global__ __launch_bounds__(256) void gmem_kernel_fb(PArgs p) {
  __shared__ __align__(16) char SM[30720];
  gmem_body(p, blockIdx.x + blockIdx.y * 8, SM);
}

__global__ __launch_bounds__(256) void maxpart_kernel_fb(PArgs p) {
  __shared__ __align__(16) char SM[1024];
  maxpart_body(p, blockIdx.x, SM);
}

__global__ __launch_bounds__(256) void out_kernel_fb(PArgs p) {
  __shared__ __align__(16) char SM[2576];
  out_body(p, blockIdx.x, SM);
}

// ============================================================ host launcher
extern "C" void kernel_launch(void* const* d_in, const int* in_sizes, int n_in,
                              void* d_out, int out_size, void* d_ws, size_t ws_size,
                              hipStream_t stream)
{
  const float* x      = (const float*)d_in[0];
  const float* Wih_l  = (const float*)d_in[1];
  const float* Whh_l  = (const float*)d_in[2];
  const float* bih_l  = (const float*)d_in[3];
  const float* bhh_l  = (const float*)d_in[4];
  const float* Wih_a  = (const float*)d_in[5];
  const float* Whh_a  = (const float*)d_in[6];
  const float* bih_a  = (const float*)d_in[7];
  const float* bhh_a  = (const float*)d_in[8];
  const float* Wih_v  = (const float*)d_in[9];
  const float* Whh_v  = (const float*)d_in[10];
  const float* bih_v  = (const float*)d_in[11];
  const float* bhh_v  = (const float*)d_in[12];
  const float* att1_w1 = (const float*)d_in[13];
  const float* att1_b1 = (const float*)d_in[14];
  const float* att1_w2 = (const float*)d_in[15];
  const float* att1_b2 = (const float*)d_in[16];
  const float* att2_w1 = (const float*)d_in[17];
  const float* att2_b1 = (const float*)d_in[18];
  const float* att2_w2 = (const float*)d_in[19];
  const float* att2_b2 = (const float*)d_in[20];
  const float* g1_w1  = (const float*)d_in[21];
  const float* g1_b1  = (const float*)d_in[22];
  const float* g1_w2  = (const float*)d_in[23];
  const float* g1_b2  = (const float*)d_in[24];
  const float* g2_w1  = (const float*)d_in[25];
  const float* g2_b1  = (const float*)d_in[26];
  const float* g2_w2  = (const float*)d_in[27];
  const float* g2_b2  = (const float*)d_in[28];
  const float* fl_w   = (const float*)d_in[29];
  const float* fl_b   = (const float*)d_in[30];
  const float* fa_w   = (const float*)d_in[31];
  const float* fa_b   = (const float*)d_in[32];
  const float* fv_w   = (const float*)d_in[33];
  const float* fv_b   = (const float*)d_in[34];
  const float* o_w1   = (const float*)d_in[35];
  const float* o_b1   = (const float*)d_in[36];
  const float* o_w2   = (const float*)d_in[37];
  const float* o_b2   = (const float*)d_in[38];

  char* base = (char*)d_ws;
  PArgs pa;
  pa.x = x;
  pa.bih_l = bih_l; pa.bhh_l = bhh_l;
  pa.bih_a = bih_a; pa.bhh_a = bhh_a;
  pa.bih_v = bih_v; pa.bhh_v = bhh_v;
  pa.att1_b1 = att1_b1; pa.att1_b2 = att1_b2;
  pa.att2_b1 = att2_b1; pa.att2_b2 = att2_b2;
  pa.g1_b1 = g1_b1; pa.g1_b2 = g1_b2;
  pa.g2_b1 = g2_b1; pa.g2_b2 = g2_b2;
  pa.fl_b = fl_b; pa.fa_b = fa_b; pa.fv_b = fv_b;
  pa.o_w1 = o_w1; pa.o_b1 = o_b1; pa.o_w2 = o_w2; pa.o_b2 = o_b2;

  const float* csrc[17] = { Wih_l, Whh_l, Wih_a, Whh_a, Wih_v, Whh_v,
                            att1_w1, att1_w2, att2_w1, att2_w2,
                            g1_w1, g1_w2, g2_w1, g2_w2, fl_w, fa_w, fv_w };
  const unsigned cdst[17] = { OFF_WIHP_L, OFF_WHH_L, OFF_WIHP_A, OFF_WHH_A,
                              OFF_WIHP_V, OFF_WHH_V, OFF_ATT1W1, OFF_ATT1W2,
                              OFF_ATT2W1, OFF_ATT2W2, OFF_G1W1, OFF_G1W2,
                              OFF_G2W1, OFF_G2W2, OFF_FLW, OFF_FAW, OFF_FVW };
  const int cK[17]   = { 300, 256, 128, 128, 128, 128, 1024, 512, 1024, 512,
                         1280, 512, 1280, 512, 256, 128, 128 };
  const int cKp[17]  = { 320, 256, 128, 128, 128, 128, 1024, 512, 1024, 512,
                         1280, 512, 1280, 512, 256, 128, 128 };
  const int cR[17]   = { 1024, 1024, 512, 512, 512, 512, 512, 1024, 512, 256,
                         512, 256, 512, 256, 128, 128, 128 };
  for (int i = 0; i < 17; i++) {
    pa.cvt_src[i] = csrc[i]; pa.cvt_dst[i] = cdst[i];
    pa.cvt_K[i] = cK[i]; pa.cvt_Kpad[i] = cKp[i]; pa.cvt_rows[i] = cR[i];
  }

  pa.POOL  = (bf16_t*)(base);
  pa.XL    = (bf16_t*)(base + 8388608);
  pa.XA    = (bf16_t*)(base + 29360128);
  pa.XV    = (bf16_t*)(base + 37748736);
  pa.HB0   = (bf16_t*)(base + 46137344);
  pa.HB1   = (bf16_t*)(base + 46661632);
  pa.CBUF  = (float*) (base + 47185920);
  pa.MEMF  = (float*) (base + 48234496);
  pa.MEMBF = (bf16_t*)(base + 48758784);
  pa.CSTAR = (bf16_t*)(base + 49020928);
  pa.Z1    = (bf16_t*)(base + 50069504);
  pa.LOGB  = (float*) (base + 50593792);
  pa.ATTD  = (bf16_t*)(base + 52690944);
  pa.Z3    = (bf16_t*)(base + 53739520);
  pa.PL    = (float*) (base + 55312384);
  pa.MAXP  = (float*) (base + 56098816);  // 48 floats
  pa.BSUM  = (float*) (base + 56099072);
  pa.BAR   = (unsigned*)(base + 56107264); // 129 u32 padded to 1 KiB
  pa.out   = (float*)d_out;

  // barrier counters must be zero at kernel start (each run)
  hipMemsetAsync(pa.BAR, 0, 1024, stream);

  void* kargs[] = { (void*)&pa };
  hipError_t e = hipLaunchCooperativeKernel((const void*)persist_kernel,
                                            dim3(GRIDP), dim3(256), kargs, 0, stream);
  if (e == hipSuccess) return;

  // ---------------- fallback: original multi-kernel schedule
  zero_kernel<<<704, 256, 0, stream>>>((float4*)pa.HB0, 180224);
  cvt_x_kernel<<<TSTEPS * NB, 256, 0, stream>>>(x, pa.XL, pa.XA, pa.XV);
  for (int i = 0; i < 17; i++)
    cvt_pad_kernel<<<cR[i], 256, 0, stream>>>(csrc[i], pa.POOL + cdst[i], cK[i], cKp[i]);
  bias_sum_kernel<<<8, 256, 0, stream>>>(bih_l, bhh_l, bih_a, bhh_a, bih_v, bhh_v, pa.BSUM);

  for (int t = 0; t < TSTEPS; t++) {
    gates_cell_kernel_fb<<<dim3(8, 16), 256, 0, stream>>>(pa, t);
    mfma_lin_kernel_fb<<<dim3(8, 8), 256, 0, stream>>>(
        pa.CSTAR, 1024, pa.POOL + OFF_ATT1W1, 1024, att1_b1,
        pa.Z1, (float*)nullptr, 512, 1024, 1);
    mfma_lin_kernel_fb<<<dim3(8, 16), 256, 0, stream>>>(
        pa.Z1, 512, pa.POOL + OFF_ATT1W2, 512, att1_b2,
        (bf16_t*)nullptr, pa.LOGB, 1024, 512, 0);
    softmax_attend_kernel_fb<<<512, 256, 0, stream>>>(pa);
    z3_kernel_fb<<<dim3(8, 24), 256, 0, stream>>>(pa);
    gmem_kernel_fb<<<dim3(8, 4), 256, 0, stream>>>(pa);
  }

  bf16_t* h_l = pa.HB0;
  bf16_t* h_a = pa.HB0 + 131072;
  bf16_t* h_v = pa.HB0 + 196608;
  mfma_lin_kernel_fb<<<dim3(8, 2), 256, 0, stream>>>(
      h_l, 256, pa.POOL + OFF_FLW, 256, fl_b, (bf16_t*)nullptr, pa.PL, 384, 256, 0);
  mfma_lin_kernel_fb<<<dim3(8, 2), 256, 0, stream>>>(
      h_a, 128, pa.POOL + OFF_FAW, 128, fa_b, (bf16_t*)nullptr, pa.PL + 128, 384, 128, 0);
  mfma_lin_kernel_fb<<<dim3(8, 2), 256, 0, stream>>>(
      h_v, 128, pa.POOL + OFF_FVW, 128, fv_b, (bf16_t*)nullptr, pa.PL + 256, 384, 128, 0);
  maxpart_kernel_fb<<<48, 256, 0, stream>>>(pa);
  out_kernel_fb<<<512, 256, 0, stream>>>(pa);
}

// Round 2
// 4829.098 us; speedup vs baseline: 2.1041x; 2.1041x over previous
//
#include <hip/hip_runtime.h>
#include <string.h>

// ---------------------------------------------------------------- types
typedef __bf16 bf16_t;
typedef bf16_t bf16x8 __attribute__((ext_vector_type(8)));
typedef bf16_t bf16x4 __attribute__((ext_vector_type(4)));
typedef float  f32x4  __attribute__((ext_vector_type(4)));

#define MFMA16(a,b,c) __builtin_amdgcn_mfma_f32_16x16x32_bf16((a),(b),(c),0,0,0)

// Problem dims
#define TSTEPS 64
#define NB     512
#define DIN    556
#define LDSK   40
#define GRIDP  256   // persistent grid: 256 blocks x 256 threads
#define GXD    33    // padded Gx stride (breaks 16-way bank conflicts)

// HW_REG_XCC_ID (id=20, offset=0, width=4) -> getreg imm encoding
#define HWREG_XCC_ID (20 | (0 << 6) | ((4 - 1) << 11))

// bf16 weight-pool element offsets
#define OFF_WIHP_L 0u
#define OFF_WHH_L  327680u
#define OFF_WIHP_A 589824u
#define OFF_WHH_A  655360u
#define OFF_WIHP_V 720896u
#define OFF_WHH_V  786432u
#define OFF_ATT1W1 851968u
#define OFF_ATT1W2 1376256u
#define OFF_ATT2W1 1900544u
#define OFF_ATT2W2 2424832u
#define OFF_G1W1   2555904u
#define OFF_G1W2   3211264u
#define OFF_G2W1   3342336u
#define OFF_G2W2   3997696u
#define OFF_FLW    4128768u
#define OFF_FAW    4161536u
#define OFF_FVW    4177920u

__device__ __forceinline__ float sigmoidf_(float x) {
  return 1.0f / (1.0f + __expf(-x));
}
__device__ __forceinline__ float tanhf_(float x) {
  x = fminf(fmaxf(x, -15.0f), 15.0f);
  float e = __expf(2.0f * x);
  return (e - 1.0f) / (e + 1.0f);
}

// ============================================================ PArgs
struct PArgs {
  const float* x;
  const float* bih_l; const float* bhh_l;
  const float* bih_a; const float* bhh_a;
  const float* bih_v; const float* bhh_v;
  const float* att1_b1; const float* att1_b2;
  const float* att2_b1; const float* att2_b2;
  const float* g1_b1; const float* g1_b2;
  const float* g2_b1; const float* g2_b2;
  const float* fl_b; const float* fa_b; const float* fv_b;
  const float* o_w1; const float* o_b1; const float* o_w2; const float* o_b2;
  // weight conversion table
  const float* cvt_src[17];
  unsigned cvt_dst[17];
  int cvt_K[17]; int cvt_Kpad[17]; int cvt_rows[17];
  // workspace
  bf16_t* POOL; bf16_t* XL; bf16_t* XA; bf16_t* XV;
  bf16_t* HB0; bf16_t* HB1; float* CBUF; float* MEMF; bf16_t* MEMBF;
  bf16_t* CSTAR; bf16_t* Z1; float* LOGB; bf16_t* ATTD; bf16_t* Z3;
  float* PL; float* MAXP; float* BSUM;
  unsigned* BAR;
  float* out;
};

// BAR layout (unsigned indices): [0..127] global group ctrs (stride 16),
// [128] global root, [159] poison flag, [160+g*16] XCD assign counters,
// [288+g*16] XCD-local barrier counters. memset 2048 B before launch.

// ============================================================ global barrier
// Full cross-XCD barrier (expensive: agent fences flush/invalidate L2).
// Used 4x total in local mode; per-phase in fallback global mode.
__device__ __forceinline__ void gbar(unsigned* bar, unsigned k, int bid) {
  __syncthreads();
  if (threadIdx.x == 0) {
    __threadfence();   // release: wb L2 so other XCDs see our writes
    unsigned* gc   = bar + (bid & 7) * 16;
    unsigned* root = bar + 128;
    if (__hip_atomic_fetch_add(gc, 1u, __ATOMIC_ACQ_REL, __HIP_MEMORY_SCOPE_AGENT)
        == 32u * (k + 1u) - 1u) {
      __hip_atomic_fetch_add(root, 1u, __ATOMIC_ACQ_REL, __HIP_MEMORY_SCOPE_AGENT);
    }
    while (__hip_atomic_load(root, __ATOMIC_RELAXED, __HIP_MEMORY_SCOPE_AGENT)
           < 8u * (k + 1u)) {
      __builtin_amdgcn_s_sleep(1);
    }
    __threadfence();   // acquire: inv L1+L2 stale lines
  }
  __syncthreads();
}

// ============================================================ XCD-local barrier
// All participating blocks are physically on ONE XCD (verified via XCC_ID),
// whose L2 is shared+coherent across its CUs and L1 is write-through.
// Release: writes drained to L2 (vmcnt 0).  Acquire: invalidate L1 only.
// NO L2 writeback/invalidate -> no 9 MB refill per barrier.
__device__ __forceinline__ void lbar(unsigned* ctr, unsigned target) {
  asm volatile("s_waitcnt vmcnt(0)" ::: "memory");
  __syncthreads();
  if (threadIdx.x == 0) {
    __hip_atomic_fetch_add(ctr, 1u, __ATOMIC_RELAXED, __HIP_MEMORY_SCOPE_AGENT);
    while (__hip_atomic_load(ctr, __ATOMIC_RELAXED, __HIP_MEMORY_SCOPE_AGENT)
           < target) {
      __builtin_amdgcn_s_sleep(1);
    }
    asm volatile("buffer_inv\n\ts_waitcnt vmcnt(0)" ::: "memory");  // L1 inv
  }
  __syncthreads();
}

// ============================================================ phase bodies
// ---- gates + cell (job in [0,128): m-tile = job>>4, y = job&15)
__device__ __forceinline__ void gates_body(const PArgs& p, int job, int t, char* SM) {
  bf16_t* Al = (bf16_t*)SM;                         // 64*40*2   = 5120
  bf16_t* Wl = (bf16_t*)(SM + 5120);                // 128*40*2  = 10240
  float (*Gx)[64][GXD] = (float (*)[64][GXD])(SM + 15360); // 4*64*33*4 = 33792

  const int tid = threadIdx.x;
  const int m0 = (job >> 4) * 64;
  const int y  = job & 15;

  const bf16_t* hin = (t & 1) ? p.HB1 : p.HB0;
  bf16_t* hout      = (t & 1) ? p.HB0 : p.HB1;

  const bf16_t *xp, *Wih, *Whh;
  int Kx, Hm, hoff, j0, oldbase, boff;
  if (y < 8) {
    xp = p.XL + (size_t)t * NB * 320; Wih = p.POOL + OFF_WIHP_L; Whh = p.POOL + OFF_WHH_L;
    Kx = 320; Hm = 256; hoff = 0; j0 = y * 32; oldbase = 0; boff = 0;
  } else if (y < 12) {
    xp = p.XA + (size_t)t * NB * 128; Wih = p.POOL + OFF_WIHP_A; Whh = p.POOL + OFF_WHH_A;
    Kx = 128; Hm = 128; hoff = 131072; j0 = (y - 8) * 32; oldbase = 256; boff = 1024;
  } else {
    xp = p.XV + (size_t)t * NB * 128; Wih = p.POOL + OFF_WIHP_V; Whh = p.POOL + OFF_WHH_V;
    Kx = 128; Hm = 128; hoff = 196608; j0 = (y - 12) * 32; oldbase = 384; boff = 1536;
  }

  const int wave = tid >> 6, lane = tid & 63;
  const int lrow = lane & 15, quad = lane >> 4;
  const int srow = tid >> 2, schunk = (tid & 3) * 8;
  const int wrow = tid >> 1, wchunk = (tid & 1) * 16;

  f32x4 acc[4][2];
  #pragma unroll
  for (int mi = 0; mi < 4; mi++)
    #pragma unroll
    for (int ni = 0; ni < 2; ni++) acc[mi][ni] = f32x4{0.f, 0.f, 0.f, 0.f};

  const int g = wrow >> 5, jr = wrow & 31;

  for (int ph = 0; ph < 2; ph++) {
    const bf16_t* Ab; const bf16_t* Wb; int lda_, ldw_, K_;
    if (ph == 0) { Ab = xp;           lda_ = Kx; K_ = Kx; Wb = Wih; ldw_ = Kx; }
    else         { Ab = hin + hoff;   lda_ = Hm; K_ = Hm; Wb = Whh; ldw_ = Hm; }

    const bf16_t* Arow = Ab + (size_t)(m0 + srow) * lda_ + schunk;
    const bf16_t* Wrow = Wb + (size_t)(g * Hm + j0 + jr) * ldw_ + wchunk;
    bf16x8 av  = *(const bf16x8*)(Arow);
    bf16x8 wv0 = *(const bf16x8*)(Wrow);
    bf16x8 wv1 = *(const bf16x8*)(Wrow + 8);

    for (int k0 = 0; k0 < K_; k0 += 32) {
      *(bf16x8*)(Al + srow * LDSK + schunk) = av;
      *(bf16x8*)(Wl + wrow * LDSK + wchunk) = wv0;
      *(bf16x8*)(Wl + wrow * LDSK + wchunk + 8) = wv1;
      __syncthreads();
      if (k0 + 32 < K_) {   // prefetch next K-tile (hides load under MFMA)
        av  = *(const bf16x8*)(Arow + k0 + 32);
        wv0 = *(const bf16x8*)(Wrow + k0 + 32);
        wv1 = *(const bf16x8*)(Wrow + k0 + 40);
      }
      bf16x8 afr[4], bfr[2];
      #pragma unroll
      for (int mi = 0; mi < 4; mi++)
        afr[mi] = *(const bf16x8*)(Al + (mi * 16 + lrow) * LDSK + quad * 8);
      #pragma unroll
      for (int ni = 0; ni < 2; ni++)
        bfr[ni] = *(const bf16x8*)(Wl + (wave * 32 + ni * 16 + lrow) * LDSK + quad * 8);
      #pragma unroll
      for (int mi = 0; mi < 4; mi++)
        #pragma unroll
        for (int ni = 0; ni < 2; ni++)
          acc[mi][ni] = MFMA16(afr[mi], bfr[ni], acc[mi][ni]);
      __syncthreads();
    }
  }

  #pragma unroll
  for (int mi = 0; mi < 4; mi++)
    #pragma unroll
    for (int ni = 0; ni < 2; ni++) {
      int col = ni * 16 + lrow;
      float bv = p.BSUM[boff + wave * Hm + j0 + col];
      #pragma unroll
      for (int r = 0; r < 4; r++) {
        Gx[wave][mi * 16 + quad * 4 + r][col] = acc[mi][ni][r] + bv;
      }
    }
  __syncthreads();

  float* cbuf = p.CBUF + hoff;
  int m = tid >> 2, jb = (tid & 3) * 8;
  #pragma unroll
  for (int i = 0; i < 8; i++) {
    int j = jb + i;
    float gi = Gx[0][m][j], gf = Gx[1][m][j], gg = Gx[2][m][j], go = Gx[3][m][j];
    size_t off = (size_t)(m0 + m) * Hm + (j0 + j);
    float c_old = cbuf[off];
    float c2 = sigmoidf_(gf) * c_old + sigmoidf_(gi) * tanhf_(gg);
    float h2 = sigmoidf_(go) * tanhf_(c2);
    cbuf[off] = c2;
    hout[hoff + off] = (bf16_t)h2;
    size_t cs = (size_t)(m0 + m) * 1024 + oldbase + (j0 + j);
    p.CSTAR[cs] = (bf16_t)c_old;
    p.CSTAR[cs + 512] = (bf16_t)c2;
  }
  __syncthreads();
}

// ---- generic 64x64 lin tile: C = act(A @ W^T + b)
__device__ __forceinline__ void lin_body(
    const bf16_t* __restrict__ A, int lda,
    const bf16_t* __restrict__ W, int ldw,
    const float* __restrict__ bias,
    bf16_t* Cb, float* Cf, int ldc, int K, int act,
    int m0, int n0, char* SM)
{
  bf16_t* Al = (bf16_t*)SM;           // 5120
  bf16_t* Wl = (bf16_t*)(SM + 5120);  // 5120
  const int tid = threadIdx.x;
  const int wave = tid >> 6, lane = tid & 63;
  const int wm = (wave >> 1) * 32, wn = (wave & 1) * 32;
  const int lrow = lane & 15, quad = lane >> 4;
  const int srow = tid >> 2, schunk = (tid & 3) * 8;

  f32x4 acc[2][2];
  #pragma unroll
  for (int mi = 0; mi < 2; mi++)
    #pragma unroll
    for (int ni = 0; ni < 2; ni++) acc[mi][ni] = f32x4{0.f, 0.f, 0.f, 0.f};

  const bf16_t* Arow = A + (size_t)(m0 + srow) * lda + schunk;
  const bf16_t* Wrow = W + (size_t)(n0 + srow) * ldw + schunk;
  bf16x8 av = *(const bf16x8*)(Arow);
  bf16x8 wv = *(const bf16x8*)(Wrow);

  for (int k0 = 0; k0 < K; k0 += 32) {
    *(bf16x8*)(Al + srow * LDSK + schunk) = av;
    *(bf16x8*)(Wl + srow * LDSK + schunk) = wv;
    __syncthreads();
    if (k0 + 32 < K) {
      av = *(const bf16x8*)(Arow + k0 + 32);
      wv = *(const bf16x8*)(Wrow + k0 + 32);
    }
    bf16x8 a0 = *(const bf16x8*)(Al + (wm + lrow) * LDSK + quad * 8);
    bf16x8 a1 = *(const bf16x8*)(Al + (wm + 16 + lrow) * LDSK + quad * 8);
    bf16x8 b0 = *(const bf16x8*)(Wl + (wn + lrow) * LDSK + quad * 8);
    bf16x8 b1 = *(const bf16x8*)(Wl + (wn + 16 + lrow) * LDSK + quad * 8);
    acc[0][0] = MFMA16(a0, b0, acc[0][0]);
    acc[0][1] = MFMA16(a0, b1, acc[0][1]);
    acc[1][0] = MFMA16(a1, b0, acc[1][0]);
    acc[1][1] = MFMA16(a1, b1, acc[1][1]);
    __syncthreads();
  }
  #pragma unroll
  for (int mi = 0; mi < 2; mi++)
    #pragma unroll
    for (int ni = 0; ni < 2; ni++) {
      int row0 = m0 + wm + mi * 16 + quad * 4;
      int col = n0 + wn + ni * 16 + lrow;
      float bv = bias[col];
      #pragma unroll
      for (int r = 0; r < 4; r++) {
        float v = acc[mi][ni][r] + bv;
        if (act == 1) v = fmaxf(v, 0.f);
        size_t off = (size_t)(row0 + r) * ldc + col;
        if (Cb) Cb[off] = (bf16_t)v;
        if (Cf) Cf[off] = v;
      }
    }
}

// ---- softmax over 1024 + attended (job = row n)
__device__ __forceinline__ void softmax_body(const PArgs& p, int n, char* SM) {
  float* red = (float*)SM;
  const int tid = threadIdx.x;
  float4 v = *(const float4*)(p.LOGB + (size_t)n * 1024 + tid * 4);
  float mx = fmaxf(fmaxf(v.x, v.y), fmaxf(v.z, v.w));
  red[tid] = mx; __syncthreads();
  for (int s = 128; s > 0; s >>= 1) {
    if (tid < s) red[tid] = fmaxf(red[tid], red[tid + s]);
    __syncthreads();
  }
  mx = red[0]; __syncthreads();
  float e0 = __expf(v.x - mx), e1 = __expf(v.y - mx);
  float e2 = __expf(v.z - mx), e3 = __expf(v.w - mx);
  red[tid] = e0 + e1 + e2 + e3; __syncthreads();
  for (int s = 128; s > 0; s >>= 1) {
    if (tid < s) red[tid] += red[tid + s];
    __syncthreads();
  }
  float inv = 1.0f / red[0];
  bf16x4 c4 = *(const bf16x4*)(p.CSTAR + (size_t)n * 1024 + tid * 4);
  bf16x4 o;
  o[0] = (bf16_t)(e0 * inv * (float)c4[0]);
  o[1] = (bf16_t)(e1 * inv * (float)c4[1]);
  o[2] = (bf16_t)(e2 * inv * (float)c4[2]);
  o[3] = (bf16_t)(e3 * inv * (float)c4[3]);
  *(bf16x4*)(p.ATTD + (size_t)n * 1024 + tid * 4) = o;
  __syncthreads();   // red reuse guard
}

// ---- merged z2|zg1|zg2 (job: m=job&7, ny=job>>3)
__device__ __forceinline__ void z3_body(const PArgs& p, int job, char* SM) {
  bf16_t* Al = (bf16_t*)SM;
  bf16_t* Wl = (bf16_t*)(SM + 5120);
  const int tid = threadIdx.x;
  const int m0 = (job & 7) * 64, n0 = (job >> 3) * 64;
  const int wave = tid >> 6, lane = tid & 63;
  const int wm = (wave >> 1) * 32, wn = (wave & 1) * 32;
  const int lrow = lane & 15, quad = lane >> 4;
  const int srow = tid >> 2, schunk = (tid & 3) * 8;

  const bf16_t* W; const float* b; int K, nloc;
  if (n0 < 512)       { W = p.POOL + OFF_ATT2W1; b = p.att2_b1; K = 1024; nloc = n0; }
  else if (n0 < 1024) { W = p.POOL + OFF_G1W1;  b = p.g1_b1;  K = 1280; nloc = n0 - 512; }
  else                { W = p.POOL + OFF_G2W1;  b = p.g2_b1;  K = 1280; nloc = n0 - 1024; }

  f32x4 acc[2][2];
  #pragma unroll
  for (int mi = 0; mi < 2; mi++)
    #pragma unroll
    for (int ni = 0; ni < 2; ni++) acc[mi][ni] = f32x4{0.f, 0.f, 0.f, 0.f};

  const bf16_t* Aatt = p.ATTD + (size_t)(m0 + srow) * 1024 + schunk;
  const bf16_t* Amem = p.MEMBF + (size_t)(m0 + srow) * 256 + schunk;
  const bf16_t* Wrow = W + (size_t)(nloc + srow) * K + schunk;
  bf16x8 av = *(const bf16x8*)(Aatt);
  bf16x8 wv = *(const bf16x8*)(Wrow);

  for (int k0 = 0; k0 < K; k0 += 32) {
    *(bf16x8*)(Al + srow * LDSK + schunk) = av;
    *(bf16x8*)(Wl + srow * LDSK + schunk) = wv;
    __syncthreads();
    int kn = k0 + 32;
    if (kn < K) {
      av = (kn < 1024) ? *(const bf16x8*)(Aatt + kn)
                       : *(const bf16x8*)(Amem + (kn - 1024));
      wv = *(const bf16x8*)(Wrow + kn);
    }
    bf16x8 a0 = *(const bf16x8*)(Al + (wm + lrow) * LDSK + quad * 8);
    bf16x8 a1 = *(const bf16x8*)(Al + (wm + 16 + lrow) * LDSK + quad * 8);
    bf16x8 b0 = *(const bf16x8*)(Wl + (wn + lrow) * LDSK + quad * 8);
    bf16x8 b1 = *(const bf16x8*)(Wl + (wn + 16 + lrow) * LDSK + quad * 8);
    acc[0][0] = MFMA16(a0, b0, acc[0][0]);
    acc[0][1] = MFMA16(a0, b1, acc[0][1]);
    acc[1][0] = MFMA16(a1, b0, acc[1][0]);
    acc[1][1] = MFMA16(a1, b1, acc[1][1]);
    __syncthreads();
  }
  #pragma unroll
  for (int mi = 0; mi < 2; mi++)
    #pragma unroll
    for (int ni = 0; ni < 2; ni++) {
      int row0 = m0 + wm + mi * 16 + quad * 4;
      int cloc = wn + ni * 16 + lrow;
      float bv = b[nloc + cloc];
      #pragma unroll
      for (int r = 0; r < 4; r++) {
        float v = fmaxf(acc[mi][ni][r] + bv, 0.f);
        p.Z3[(size_t)(row0 + r) * 1536 + n0 + cloc] = (bf16_t)v;
      }
    }
}

// ---- cHat/gamma1/gamma2 GEMMs + mem update (job: m=job&7, ny=job>>3)
__device__ __forceinline__ void gmem_body(const PArgs& p, int job, char* SM) {
  const int tid = threadIdx.x;
  const int m0 = (job & 7) * 64, n0 = (job >> 3) * 64;
  const int wave = tid >> 6, lane = tid & 63;
  const int wm = (wave >> 1) * 32, wn = (wave & 1) * 32;
  const int lrow = lane & 15, quad = lane >> 4;
  const int srow = tid >> 2, schunk = (tid & 3) * 8;

  const bf16_t* Ws[3] = { p.POOL + OFF_ATT2W2, p.POOL + OFF_G1W2, p.POOL + OFF_G2W2 };

  f32x4 acc[3][2][2];
  #pragma unroll
  for (int s = 0; s < 3; s++)
    #pragma unroll
    for (int mi = 0; mi < 2; mi++)
      #pragma unroll
      for (int ni = 0; ni < 2; ni++) acc[s][mi][ni] = f32x4{0.f, 0.f, 0.f, 0.f};

  const bf16_t* Arow = p.Z3 + (size_t)(m0 + srow) * 1536 + schunk;
  bf16x8 avv[3], wvv[3];
  #pragma unroll
  for (int s = 0; s < 3; s++) {
    avv[s] = *(const bf16x8*)(Arow + s * 512);
    wvv[s] = *(const bf16x8*)(Ws[s] + (size_t)(n0 + srow) * 512 + schunk);
  }

  for (int k0 = 0; k0 < 512; k0 += 32) {
    #pragma unroll
    for (int s = 0; s < 3; s++) {
      bf16_t* Az = (bf16_t*)(SM + s * 5120);
      bf16_t* Wz = (bf16_t*)(SM + 15360 + s * 5120);
      *(bf16x8*)(Az + srow * LDSK + schunk) = avv[s];
      *(bf16x8*)(Wz + srow * LDSK + schunk) = wvv[s];
    }
    __syncthreads();
    if (k0 + 32 < 512) {
      #pragma unroll
      for (int s = 0; s < 3; s++) {
        avv[s] = *(const bf16x8*)(Arow + s * 512 + k0 + 32);
        wvv[s] = *(const bf16x8*)(Ws[s] + (size_t)(n0 + srow) * 512 + k0 + 32 + schunk);
      }
    }
    #pragma unroll
    for (int s = 0; s < 3; s++) {
      bf16_t* Az = (bf16_t*)(SM + s * 5120);
      bf16_t* Wz = (bf16_t*)(SM + 15360 + s * 5120);
      bf16x8 a0 = *(const bf16x8*)(Az + (wm + lrow) * LDSK + quad * 8);
      bf16x8 a1 = *(const bf16x8*)(Az + (wm + 16 + lrow) * LDSK + quad * 8);
      bf16x8 b0 = *(const bf16x8*)(Wz + (wn + lrow) * LDSK + quad * 8);
      bf16x8 b1 = *(const bf16x8*)(Wz + (wn + 16 + lrow) * LDSK + quad * 8);
      acc[s][0][0] = MFMA16(a0, b0, acc[s][0][0]);
      acc[s][0][1] = MFMA16(a0, b1, acc[s][0][1]);
      acc[s][1][0] = MFMA16(a1, b0, acc[s][1][0]);
      acc[s][1][1] = MFMA16(a1, b1, acc[s][1][1]);
    }
    __syncthreads();
  }
  #pragma unroll
  for (int mi = 0; mi < 2; mi++)
    #pragma unroll
    for (int ni = 0; ni < 2; ni++) {
      int row0 = m0 + wm + mi * 16 + quad * 4;
      int col = n0 + wn + ni * 16 + lrow;
      float bC = p.att2_b2[col], b1v = p.g1_b2[col], b2v = p.g2_b2[col];
      #pragma unroll
      for (int r = 0; r < 4; r++) {
        float cHat = tanhf_(acc[0][mi][ni][r] + bC);
        float g1 = sigmoidf_(acc[1][mi][ni][r] + b1v);
        float g2 = sigmoidf_(acc[2][mi][ni][r] + b2v);
        size_t off = (size_t)(row0 + r) * 256 + col;
        float nm = g1 * p.MEMF[off] + g2 * cHat;
        p.MEMF[off] = nm;
        p.MEMBF[off] = (bf16_t)nm;
      }
    }
}

// ---- partial max (job in [0,48))
__device__ __forceinline__ void maxpart_body(const PArgs& p, int job, char* SM) {
  float* red = (float*)SM;
  const int b = job >> 4, chunk = job & 15;
  const int tid = threadIdx.x;
  float mx = -3.4e38f;
  for (int i = tid; i < 32 * 128; i += 256) {
    int n = chunk * 32 + (i >> 7), j = i & 127;
    mx = fmaxf(mx, p.PL[(size_t)n * 384 + b * 128 + j]);
  }
  red[tid] = mx; __syncthreads();
  for (int s = 128; s > 0; s >>= 1) {
    if (tid < s) red[tid] = fmaxf(red[tid], red[tid + s]);
    __syncthreads();
  }
  if (tid == 0) p.MAXP[job] = red[0];
  __syncthreads();
}

// ---- final output row (job = row n)
__device__ __forceinline__ void out_body(const PArgs& p, int n, char* SM) {
  float* hs  = (float*)SM;
  float* red = (float*)(SM + 1536);
  float* Ms  = (float*)(SM + 2560);
  const int tid = threadIdx.x;
  if (tid < 3) {
    float m = -3.4e38f;
    #pragma unroll
    for (int i = 0; i < 16; i++) m = fmaxf(m, p.MAXP[tid * 16 + i]);
    Ms[tid] = m;
  }
  __syncthreads();
  const float M0 = Ms[0], M1 = Ms[1], M2 = Ms[2];
  for (int idx = tid; idx < 384; idx += 256) {
    float v;
    if (idx < 128) {
      float d0 = p.PL[(size_t)n * 384 + idx] - M0;
      float d1 = p.PL[(size_t)n * 384 + 128 + idx] - M1;
      float d2 = p.PL[(size_t)n * 384 + 256 + idx] - M2;
      v = __expf(d0) * d0 + __expf(d1) * d1 + __expf(d2) * d2;
    } else {
      v = p.MEMF[(size_t)n * 256 + idx - 128];
    }
    hs[idx] = v;
  }
  __syncthreads();
  float acc = p.o_b1[tid];
  const float* wr = p.o_w1 + (size_t)tid * 384;
  #pragma unroll 4
  for (int k = 0; k < 384; k += 4) {
    float4 w = *(const float4*)(wr + k);
    acc += w.x * hs[k] + w.y * hs[k + 1] + w.z * hs[k + 2] + w.w * hs[k + 3];
  }
  red[tid] = fmaxf(acc, 0.f) * p.o_w2[tid];
  __syncthreads();
  for (int s = 128; s > 0; s >>= 1) {
    if (tid < s) red[tid] += red[tid + s];
    __syncthreads();
  }
  if (tid == 0) p.out[n] = red[0] + p.o_b2[0];
  __syncthreads();
}

// ============================================================ persistent
__global__ void __launch_bounds__(256) persist_kernel(PArgs p) {
  __shared__ __align__(16) char SM[49152];
  __shared__ int meta[12];   // [0]=xcd, [1]=rank, [2..9]=group counts, [10]=poison
  const int bid = blockIdx.x;
  const int tid = threadIdx.x;
  unsigned bk = 0;

  // ---------------- P0: zero state + convert inputs/weights + bias sums
  {
    float4* z = (float4*)p.HB0;
    for (int i = bid * 256 + tid; i < 180224; i += GRIDP * 256)
      z[i] = make_float4(0.f, 0.f, 0.f, 0.f);

    int gid = bid * 256 + tid;
    if (gid < 1024)      p.BSUM[gid] = p.bih_l[gid] + p.bhh_l[gid];
    else if (gid < 1536) p.BSUM[gid] = p.bih_a[gid - 1024] + p.bhh_a[gid - 1024];
    else if (gid < 2048) p.BSUM[gid] = p.bih_v[gid - 1536] + p.bhh_v[gid - 1536];

    for (int r = bid; r < TSTEPS * NB; r += GRIDP) {
      const float4* xr = (const float4*)(p.x + (size_t)r * DIN);
      int q = tid;
      if (q < 144) {
        float4 v; bf16_t* dst;
        if (q < 80) {
          v = (q < 75) ? xr[q] : make_float4(0.f, 0.f, 0.f, 0.f);
          dst = p.XL + (size_t)r * 320 + q * 4;
        } else if (q < 112) {
          v = xr[75 + (q - 80)];
          dst = p.XA + (size_t)r * 128 + (q - 80) * 4;
        } else {
          v = xr[107 + (q - 112)];
          dst = p.XV + (size_t)r * 128 + (q - 112) * 4;
        }
        bf16x4 o;
        o[0] = (bf16_t)v.x; o[1] = (bf16_t)v.y; o[2] = (bf16_t)v.z; o[3] = (bf16_t)v.w;
        *(bf16x4*)dst = o;
      }
    }

    for (int m = 0; m < 17; m++) {
      const float* src = p.cvt_src[m];
      bf16_t* dst = p.POOL + p.cvt_dst[m];
      int K = p.cvt_K[m], Kp = p.cvt_Kpad[m], R = p.cvt_rows[m];
      int Kq = Kp >> 2, Ksq = K >> 2;
      for (int r = bid; r < R; r += GRIDP) {
        const float4* sr = (const float4*)(src + (size_t)r * K);
        for (int q = tid; q < Kq; q += 256) {
          float4 v = (q < Ksq) ? sr[q] : make_float4(0.f, 0.f, 0.f, 0.f);
          bf16x4 o;
          o[0] = (bf16_t)v.x; o[1] = (bf16_t)v.y; o[2] = (bf16_t)v.z; o[3] = (bf16_t)v.w;
          *(bf16x4*)(dst + (size_t)r * Kp + q * 4) = o;
        }
      }
    }

    // XCD self-identification
    if (tid == 0) {
      unsigned raw = __builtin_amdgcn_s_getreg(HWREG_XCC_ID);
      if (raw > 7u) {
        __hip_atomic_store(p.BAR + 159, 1u, __ATOMIC_RELAXED, __HIP_MEMORY_SCOPE_AGENT);
        raw &= 7u;
      }
      meta[0] = (int)raw;
      meta[1] = (int)__hip_atomic_fetch_add(p.BAR + 160 + raw * 16, 1u,
                    __ATOMIC_RELAXED, __HIP_MEMORY_SCOPE_AGENT);
    }
  }
  gbar(p.BAR, bk++, bid);

  // read group census
  if (tid < 8)
    meta[2 + tid] = (int)__hip_atomic_load(p.BAR + 160 + tid * 16,
                        __ATOMIC_RELAXED, __HIP_MEMORY_SCOPE_AGENT);
  if (tid == 8)
    meta[10] = (int)__hip_atomic_load(p.BAR + 159,
                   __ATOMIC_RELAXED, __HIP_MEMORY_SCOPE_AGENT);
  __syncthreads();
  int total = 0; bool localmode = (meta[10] == 0);
  #pragma unroll
  for (int i = 0; i < 8; i++) {
    total += meta[2 + i];
    if (meta[2 + i] == 0) localmode = false;
  }
  if (total != GRIDP) localmode = false;

  if (localmode) {
    // ============ XCD-local recurrence: each XCD owns a 64-row slab ============
    const int g = meta[0];
    const int rank = meta[1];
    const unsigned cnt = (unsigned)meta[2 + g];
    unsigned* lctr = p.BAR + 288 + g * 16;
    unsigned lk = 0;

    for (int t = 0; t < TSTEPS; t++) {
      for (int j = rank; j < 16; j += (int)cnt) gates_body(p, g * 16 + j, t, SM);
      lbar(lctr, cnt * (++lk));

      for (int j = rank; j < 8; j += (int)cnt)
        lin_body(p.CSTAR, 1024, p.POOL + OFF_ATT1W1, 1024, p.att1_b1,
                 p.Z1, (float*)0, 512, 1024, 1, g * 64, j * 64, SM);
      lbar(lctr, cnt * (++lk));

      for (int j = rank; j < 16; j += (int)cnt)
        lin_body(p.Z1, 512, p.POOL + OFF_ATT1W2, 512, p.att1_b2,
                 (bf16_t*)0, p.LOGB, 1024, 512, 0, g * 64, j * 64, SM);
      lbar(lctr, cnt * (++lk));

      for (int j = rank; j < 64; j += (int)cnt) softmax_body(p, g * 64 + j, SM);
      lbar(lctr, cnt * (++lk));

      for (int j = rank; j < 24; j += (int)cnt) z3_body(p, (j << 3) | g, SM);
      lbar(lctr, cnt * (++lk));

      for (int j = rank; j < 4; j += (int)cnt) gmem_body(p, (j << 3) | g, SM);
      // no barrier: gmem(t) races only with gates(t+1) (disjoint buffers);
      // the gates lbar orders gmem(t) before z1/z3(t+1).
    }
  } else {
    // ============ fallback: global barriers every phase (round-1 scheme) ======
    for (int t = 0; t < TSTEPS; t++) {
      for (int job = bid; job < 128; job += GRIDP) gates_body(p, job, t, SM);
      gbar(p.BAR, bk++, bid);

      for (int job = bid; job < 64; job += GRIDP)
        lin_body(p.CSTAR, 1024, p.POOL + OFF_ATT1W1, 1024, p.att1_b1,
                 p.Z1, (float*)0, 512, 1024, 1, (job & 7) * 64, (job >> 3) * 64, SM);
      gbar(p.BAR, bk++, bid);

      for (int job = bid; job < 128; job += GRIDP)
        lin_body(p.Z1, 512, p.POOL + OFF_ATT1W2, 512, p.att1_b2,
                 (bf16_t*)0, p.LOGB, 1024, 512, 0, (job & 7) * 64, (job >> 3) * 64, SM);
      gbar(p.BAR, bk++, bid);

      for (int job = bid; job < 512; job += GRIDP) softmax_body(p, job, SM);
      gbar(p.BAR, bk++, bid);

      for (int job = bid; job < 192; job += GRIDP) z3_body(p, job, SM);
      gbar(p.BAR, bk++, bid);

      for (int job = bid; job < 32; job += GRIDP) gmem_body(p, job, SM);
    }
  }
  gbar(p.BAR, bk++, bid);   // cross-XCD: publish h, MEMF

  // ---------------- tail: PL GEMMs -> partial max -> output MLP
  for (int job = bid; job < 48; job += GRIDP) {
    int mat = job >> 4, rem = job & 15;
    int m0 = (rem & 7) * 64, n0 = (rem >> 3) * 64;
    const bf16_t* h = (mat == 0) ? p.HB0 : (mat == 1) ? p.HB0 + 131072 : p.HB0 + 196608;
    int lda = (mat == 0) ? 256 : 128;
    const bf16_t* W = p.POOL + ((mat == 0) ? OFF_FLW : (mat == 1) ? OFF_FAW : OFF_FVW);
    const float* b = (mat == 0) ? p.fl_b : (mat == 1) ? p.fa_b : p.fv_b;
    lin_body(h, lda, W, lda, b, (bf16_t*)0, p.PL + mat * 128, 384, lda, 0, m0, n0, SM);
  }
  gbar(p.BAR, bk++, bid);

  for (int job = bid; job < 48; job += GRIDP) maxpart_body(p, job, SM);
  gbar(p.BAR, bk++, bid);

  for (int job = bid; job < 512; job += GRIDP) out_body(p, job, SM);
}

// ============================================================ fallback path
// (used only if the cooperative launch is rejected)

__global__ __launch_bounds__(256) void zero_kernel(float4* p, int n4) {
  int i = blockIdx.x * 256 + threadIdx.x;
  if (i < n4) p[i] = make_float4(0.f, 0.f, 0.f, 0.f);
}

__global__ __launch_bounds__(256) void cvt_pad_kernel(
    const float* __restrict__ src, bf16_t* __restrict__ dst, int K, int Kpad)
{
  int r = blockIdx.x;
  for (int k = threadIdx.x; k < Kpad; k += 256)
    dst[(size_t)r * Kpad + k] = (k < K) ? (bf16_t)src[(size_t)r * K + k] : (bf16_t)0.f;
}

__global__ __launch_bounds__(256) void cvt_x_kernel(
    const float* __restrict__ x, bf16_t* __restrict__ xl,
    bf16_t* __restrict__ xa, bf16_t* __restrict__ xv)
{
  int r = blockIdx.x;
  const float* xr = x + (size_t)r * DIN;
  for (int c = threadIdx.x; c < 576; c += 256) {
    if (c < 320) {
      xl[(size_t)r * 320 + c] = (c < 300) ? (bf16_t)xr[c] : (bf16_t)0.f;
    } else if (c < 448) {
      xa[(size_t)r * 128 + (c - 320)] = (bf16_t)xr[300 + (c - 320)];
    } else {
      xv[(size_t)r * 128 + (c - 448)] = (bf16_t)xr[428 + (c - 448)];
    }
  }
}

__global__ __launch_bounds__(256) void bias_sum_kernel(
    const float* __restrict__ bih_l, const float* __restrict__ bhh_l,
    const float* __restrict__ bih_a, const float* __restrict__ bhh_a,
    const float* __restrict__ bih_v, const float* __restrict__ bhh_v,
    float* __restrict__ bsum)
{
  int i = blockIdx.x * 256 + threadIdx.x;
  if (i < 1024)      bsum[i] = bih_l[i] + bhh_l[i];
  else if (i < 1536) bsum[i] = bih_a[i - 1024] + bhh_a[i - 1024];
  else if (i < 2048) bsum[i] = bih_v[i - 1536] + bhh_v[i - 1536];
}

__global__ __launch_bounds__(256) void gates_cell_kernel_fb(PArgs p, int t) {
  __shared__ __align__(16) char SM[49152];
  gates_body(p, blockIdx.x * 16 + blockIdx.y, t, SM);
}

__global__ __launch_bounds__(256) void mfma_lin_kernel_fb(
    const bf16_t* A, int lda, const bf16_t* W, int ldw,
    const float* bias, bf16_t* Cb, float* Cf, int ldc, int K, int act)
{
  __shared__ __align__(16) char SM[10240];
  lin_body(A, lda, W, ldw, bias, Cb, Cf, ldc, K, act,
           blockIdx.x * 64, blockIdx.y * 64, SM);
}

__global__ __launch_bounds__(256) void softmax_attend_kernel_fb(PArgs p) {
  __shared__ __align__(16) char SM[1024];
  softmax_body(p, blockIdx.x, SM);
}

__global__ __launch_bounds__(256) void z3_kernel_fb(PArgs p) {
  __shared__ __align__(16) char SM[10240];
  z3_body(p, blockIdx.x + blockIdx.y * 8, SM);
}

__global__ __launch_bounds__(256) void gmem_kernel_fb(PArgs p) {
  __shared__ __align__(16) char SM[30720];
  gmem_body(p, blockIdx.x + blockIdx.y * 8, SM);
}

__global__ __launch_bounds__(256) void maxpart_kernel_fb(PArgs p) {
  __shared__ __align__(16) char SM[1024];
  maxpart_body(p, blockIdx.x, SM);
}

__global__ __launch_bounds__(256) void out_kernel_fb(PArgs p) {
  __shared__ __align__(16) char SM[2576];
  out_body(p, blockIdx.x, SM);
}

// ============================================================ host launcher
extern "C" void kernel_launch(void* const* d_in, const int* in_sizes, int n_in,
                              void* d_out, int out_size, void* d_ws, size_t ws_size,
                              hipStream_t stream)
{
  const float* x      = (const float*)d_in[0];
  const float* Wih_l  = (const float*)d_in[1];
  const float* Whh_l  = (const float*)d_in[2];
  const float* bih_l  = (const float*)d_in[3];
  const float* bhh_l  = (const float*)d_in[4];
  const float* Wih_a  = (const float*)d_in[5];
  const float* Whh_a  = (const float*)d_in[6];
  const float* bih_a  = (const float*)d_in[7];
  const float* bhh_a  = (const float*)d_in[8];
  const float* Wih_v  = (const float*)d_in[9];
  const float* Whh_v  = (const float*)d_in[10];
  const float* bih_v  = (const float*)d_in[11];
  const float* bhh_v  = (const float*)d_in[12];
  const float* att1_w1 = (const float*)d_in[13];
  const float* att1_b1 = (const float*)d_in[14];
  const float* att1_w2 = (const float*)d_in[15];
  const float* att1_b2 = (const float*)d_in[16];
  const float* att2_w1 = (const float*)d_in[17];
  const float* att2_b1 = (const float*)d_in[18];
  const float* att2_w2 = (const float*)d_in[19];
  const float* att2_b2 = (const float*)d_in[20];
  const float* g1_w1  = (const float*)d_in[21];
  const float* g1_b1  = (const float*)d_in[22];
  const float* g1_w2  = (const float*)d_in[23];
  const float* g1_b2  = (const float*)d_in[24];
  const float* g2_w1  = (const float*)d_in[25];
  const float* g2_b1  = (const float*)d_in[26];
  const float* g2_w2  = (const float*)d_in[27];
  const float* g2_b2  = (const float*)d_in[28];
  const float* fl_w   = (const float*)d_in[29];
  const float* fl_b   = (const float*)d_in[30];
  const float* fa_w   = (const float*)d_in[31];
  const float* fa_b   = (const float*)d_in[32];
  const float* fv_w   = (const float*)d_in[33];
  const float* fv_b   = (const float*)d_in[34];
  const float* o_w1   = (const float*)d_in[35];
  const float* o_b1   = (const float*)d_in[36];
  const float* o_w2   = (const float*)d_in[37];
  const float* o_b2   = (const float*)d_in[38];

  char* base = (char*)d_ws;
  PArgs pa;
  pa.x = x;
  pa.bih_l = bih_l; pa.bhh_l = bhh_l;
  pa.bih_a = bih_a; pa.bhh_a = bhh_a;
  pa.bih_v = bih_v; pa.bhh_v = bhh_v;
  pa.att1_b1 = att1_b1; pa.att1_b2 = att1_b2;
  pa.att2_b1 = att2_b1; pa.att2_b2 = att2_b2;
  pa.g1_b1 = g1_b1; pa.g1_b2 = g1_b2;
  pa.g2_b1 = g2_b1; pa.g2_b2 = g2_b2;
  pa.fl_b = fl_b; pa.fa_b = fa_b; pa.fv_b = fv_b;
  pa.o_w1 = o_w1; pa.o_b1 = o_b1; pa.o_w2 = o_w2; pa.o_b2 = o_b2;

  const float* csrc[17] = { Wih_l, Whh_l, Wih_a, Whh_a, Wih_v, Whh_v,
                            att1_w1, att1_w2, att2_w1, att2_w2,
                            g1_w1, g1_w2, g2_w1, g2_w2, fl_w, fa_w, fv_w };
  const unsigned cdst[17] = { OFF_WIHP_L, OFF_WHH_L, OFF_WIHP_A, OFF_WHH_A,
                              OFF_WIHP_V, OFF_WHH_V, OFF_ATT1W1, OFF_ATT1W2,
                              OFF_ATT2W1, OFF_ATT2W2, OFF_G1W1, OFF_G1W2,
                              OFF_G2W1, OFF_G2W2, OFF_FLW, OFF_FAW, OFF_FVW };
  const int cK[17]   = { 300, 256, 128, 128, 128, 128, 1024, 512, 1024, 512,
                         1280, 512, 1280, 512, 256, 128, 128 };
  const int cKp[17]  = { 320, 256, 128, 128, 128, 128, 1024, 512, 1024, 512,
                         1280, 512, 1280, 512, 256, 128, 128 };
  const int cR[17]   = { 1024, 1024, 512, 512, 512, 512, 512, 1024, 512, 256,
                         512, 256, 512, 256, 128, 128, 128 };
  for (int i = 0; i < 17; i++) {
    pa.cvt_src[i] = csrc[i]; pa.cvt_dst[i] = cdst[i];
    pa.cvt_K[i] = cK[i]; pa.cvt_Kpad[i] = cKp[i]; pa.cvt_rows[i] = cR[i];
  }

  pa.POOL  = (bf16_t*)(base);
  pa.XL    = (bf16_t*)(base + 8388608);
  pa.XA    = (bf16_t*)(base + 29360128);
  pa.XV    = (bf16_t*)(base + 37748736);
  pa.HB0   = (bf16_t*)(base + 46137344);
  pa.HB1   = (bf16_t*)(base + 46661632);
  pa.CBUF  = (float*) (base + 47185920);
  pa.MEMF  = (float*) (base + 48234496);
  pa.MEMBF = (bf16_t*)(base + 48758784);
  pa.CSTAR = (bf16_t*)(base + 49020928);
  pa.Z1    = (bf16_t*)(base + 50069504);
  pa.LOGB  = (float*) (base + 50593792);
  pa.ATTD  = (bf16_t*)(base + 52690944);
  pa.Z3    = (bf16_t*)(base + 53739520);
  pa.PL    = (float*) (base + 55312384);
  pa.MAXP  = (float*) (base + 56098816);
  pa.BSUM  = (float*) (base + 56099072);
  pa.BAR   = (unsigned*)(base + 56107264);
  pa.out   = (float*)d_out;

  // barrier/census counters must be zero at kernel start (each run)
  hipMemsetAsync(pa.BAR, 0, 2048, stream);

  void* kargs[] = { (void*)&pa };
  hipError_t e = hipLaunchCooperativeKernel((const void*)persist_kernel,
                                            dim3(GRIDP), dim3(256), kargs, 0, stream);
  if (e == hipSuccess) return;

  // ---------------- fallback: original multi-kernel schedule
  zero_kernel<<<704, 256, 0, stream>>>((float4*)pa.HB0, 180224);
  cvt_x_kernel<<<TSTEPS * NB, 256, 0, stream>>>(x, pa.XL, pa.XA, pa.XV);
  for (int i = 0; i < 17; i++)
    cvt_pad_kernel<<<cR[i], 256, 0, stream>>>(csrc[i], pa.POOL + cdst[i], cK[i], cKp[i]);
  bias_sum_kernel<<<8, 256, 0, stream>>>(bih_l, bhh_l, bih_a, bhh_a, bih_v, bhh_v, pa.BSUM);

  for (int t = 0; t < TSTEPS; t++) {
    gates_cell_kernel_fb<<<dim3(8, 16), 256, 0, stream>>>(pa, t);
    mfma_lin_kernel_fb<<<dim3(8, 8), 256, 0, stream>>>(
        pa.CSTAR, 1024, pa.POOL + OFF_ATT1W1, 1024, att1_b1,
        pa.Z1, (float*)nullptr, 512, 1024, 1);
    mfma_lin_kernel_fb<<<dim3(8, 16), 256, 0, stream>>>(
        pa.Z1, 512, pa.POOL + OFF_ATT1W2, 512, att1_b2,
        (bf16_t*)nullptr, pa.LOGB, 1024, 512, 0);
    softmax_attend_kernel_fb<<<512, 256, 0, stream>>>(pa);
    z3_kernel_fb<<<dim3(8, 24), 256, 0, stream>>>(pa);
    gmem_kernel_fb<<<dim3(8, 4), 256, 0, stream>>>(pa);
  }

  bf16_t* h_l = pa.HB0;
  bf16_t* h_a = pa.HB0 + 131072;
  bf16_t* h_v = pa.HB0 + 196608;
  mfma_lin_kernel_fb<<<dim3(8, 2), 256, 0, stream>>>(
      h_l, 256, pa.POOL + OFF_FLW, 256, fl_b, (bf16_t*)nullptr, pa.PL, 384, 256, 0);
  mfma_lin_kernel_fb<<<dim3(8, 2), 256, 0, stream>>>(
      h_a, 128, pa.POOL + OFF_FAW, 128, fa_b, (bf16_t*)nullptr, pa.PL + 128, 384, 128, 0);
  mfma_lin_kernel_fb<<<dim3(8, 2), 256, 0, stream>>>(
      h_v, 128, pa.POOL + OFF_FVW, 128, fv_b, (bf16_t*)nullptr, pa.PL + 256, 384, 128, 0);
  maxpart_kernel_fb<<<48, 256, 0, stream>>>(pa);
  out_kernel_fb<<<512, 256, 0, stream>>>(pa);
}

// Round 3
// 4449.241 us; speedup vs baseline: 2.2837x; 1.0854x over previous
//
#include <hip/hip_runtime.h>
#include <string.h>

// ---------------------------------------------------------------- types
typedef __bf16 bf16_t;
typedef bf16_t bf16x8 __attribute__((ext_vector_type(8)));
typedef bf16_t bf16x4 __attribute__((ext_vector_type(4)));
typedef float  f32x4  __attribute__((ext_vector_type(4)));

#define MFMA16(a,b,c) __builtin_amdgcn_mfma_f32_16x16x32_bf16((a),(b),(c),0,0,0)

// Problem dims
#define TSTEPS 64
#define NB     512
#define DIN    556
#define LDSK   40
#define GRIDP  256   // persistent grid: 256 blocks x 256 threads
#define GXD    33    // padded Gx stride

// HW_REG_XCC_ID (id=20, offset=0, width=4) -> getreg imm encoding
#define HWREG_XCC_ID (20 | (0 << 6) | ((4 - 1) << 11))

// bf16 weight-pool element offsets
#define OFF_WIHP_L 0u
#define OFF_WHH_L  327680u
#define OFF_WIHP_A 589824u
#define OFF_WHH_A  655360u
#define OFF_WIHP_V 720896u
#define OFF_WHH_V  786432u
#define OFF_ATT1W1 851968u
#define OFF_ATT1W2 1376256u
#define OFF_ATT2W1 1900544u
#define OFF_ATT2W2 2424832u
#define OFF_G1W1   2555904u
#define OFF_G1W2   3211264u
#define OFF_G2W1   3342336u
#define OFF_G2W2   3997696u
#define OFF_FLW    4128768u
#define OFF_FAW    4161536u
#define OFF_FVW    4177920u

__device__ __forceinline__ float sigmoidf_(float x) {
  return 1.0f / (1.0f + __expf(-x));
}
__device__ __forceinline__ float tanhf_(float x) {
  x = fminf(fmaxf(x, -15.0f), 15.0f);
  float e = __expf(2.0f * x);
  return (e - 1.0f) / (e + 1.0f);
}

// ============================================================ PArgs
struct PArgs {
  const float* x;
  const float* bih_l; const float* bhh_l;
  const float* bih_a; const float* bhh_a;
  const float* bih_v; const float* bhh_v;
  const float* att1_b1; const float* att1_b2;
  const float* att2_b1; const float* att2_b2;
  const float* g1_b1; const float* g1_b2;
  const float* g2_b1; const float* g2_b2;
  const float* fl_b; const float* fa_b; const float* fv_b;
  const float* o_w1; const float* o_b1; const float* o_w2; const float* o_b2;
  // weight conversion table
  const float* cvt_src[17];
  unsigned cvt_dst[17];
  int cvt_K[17]; int cvt_Kpad[17]; int cvt_rows[17];
  // workspace
  bf16_t* POOL; bf16_t* XL; bf16_t* XA; bf16_t* XV;
  bf16_t* HB0; bf16_t* HB1; float* CBUF; float* MEMF; bf16_t* MEMBF;
  bf16_t* CSTAR; bf16_t* CSTAR2; bf16_t* Z1; float* LOGB; bf16_t* ATTD; bf16_t* Z3;
  float* PL; float* MAXP; float* BSUM;
  unsigned* BAR;
  float* out;
  int allow_team;
};

// BAR layout (u32 idx): [0..127] global grp ctrs (stride16), [128] global root,
// [159] poison, [160+g*16] XCD census, [288+g*16] XCD full-barrier ctr,
// [416+g*16] XCD attn-team ctr.  memset 4096 B each launch.

// ============================================================ global barrier
__device__ __forceinline__ void gbar(unsigned* bar, unsigned k, int bid) {
  __syncthreads();
  if (threadIdx.x == 0) {
    __threadfence();   // release: L2 wb so other XCDs see our writes
    unsigned* gc   = bar + (bid & 7) * 16;
    unsigned* root = bar + 128;
    if (__hip_atomic_fetch_add(gc, 1u, __ATOMIC_ACQ_REL, __HIP_MEMORY_SCOPE_AGENT)
        == 32u * (k + 1u) - 1u) {
      __hip_atomic_fetch_add(root, 1u, __ATOMIC_ACQ_REL, __HIP_MEMORY_SCOPE_AGENT);
    }
    while (__hip_atomic_load(root, __ATOMIC_RELAXED, __HIP_MEMORY_SCOPE_AGENT)
           < 8u * (k + 1u)) {
      __builtin_amdgcn_s_sleep(1);
    }
    __threadfence();   // acquire
  }
  __syncthreads();
}

// ============================================================ XCD-local barrier
// Participants verified on ONE XCD (shared L2). Release: drain writes to L2.
// Acquire: invalidate L1 only. No L2 flush.
__device__ __forceinline__ void lbar(unsigned* ctr, unsigned target) {
  asm volatile("s_waitcnt vmcnt(0)" ::: "memory");
  __syncthreads();
  if (threadIdx.x == 0) {
    __hip_atomic_fetch_add(ctr, 1u, __ATOMIC_RELAXED, __HIP_MEMORY_SCOPE_AGENT);
    while (__hip_atomic_load(ctr, __ATOMIC_RELAXED, __HIP_MEMORY_SCOPE_AGENT)
           < target) {
      __builtin_amdgcn_s_sleep(1);
    }
    asm volatile("buffer_inv\n\ts_waitcnt vmcnt(0)" ::: "memory");  // L1 inv
  }
  __syncthreads();
}

// ============================================================ phase bodies
// ---- gates + cell (job: m-tile = job>>4, y = job&15). Double-buffered LDS.
__device__ __forceinline__ void gates_body(const PArgs& p, int job, int t, char* SM,
                                           const bf16_t* hbase, bf16_t* houtb,
                                           bf16_t* cstar)
{
  bf16_t* AlB[2] = { (bf16_t*)SM,            (bf16_t*)(SM + 5120) };
  bf16_t* WlB[2] = { (bf16_t*)(SM + 10240),  (bf16_t*)(SM + 20480) };
  float (*Gx)[64][GXD] = (float (*)[64][GXD])SM;   // overlays staging (after sync)

  const int tid = threadIdx.x;
  const int m0 = (job >> 4) * 64;
  const int y  = job & 15;

  const bf16_t *xp, *Wih, *Whh;
  int Kx, Hm, hoff, j0, oldbase, boff;
  if (y < 8) {
    xp = p.XL + (size_t)t * NB * 320; Wih = p.POOL + OFF_WIHP_L; Whh = p.POOL + OFF_WHH_L;
    Kx = 320; Hm = 256; hoff = 0; j0 = y * 32; oldbase = 0; boff = 0;
  } else if (y < 12) {
    xp = p.XA + (size_t)t * NB * 128; Wih = p.POOL + OFF_WIHP_A; Whh = p.POOL + OFF_WHH_A;
    Kx = 128; Hm = 128; hoff = 131072; j0 = (y - 8) * 32; oldbase = 256; boff = 1024;
  } else {
    xp = p.XV + (size_t)t * NB * 128; Wih = p.POOL + OFF_WIHP_V; Whh = p.POOL + OFF_WHH_V;
    Kx = 128; Hm = 128; hoff = 196608; j0 = (y - 12) * 32; oldbase = 384; boff = 1536;
  }

  const int wave = tid >> 6, lane = tid & 63;
  const int lrow = lane & 15, quad = lane >> 4;
  const int srow = tid >> 2, schunk = (tid & 3) * 8;
  const int wrow = tid >> 1, wchunk = (tid & 1) * 16;
  const int g = wrow >> 5, jr = wrow & 31;

  f32x4 acc[4][2];
  #pragma unroll
  for (int mi = 0; mi < 4; mi++)
    #pragma unroll
    for (int ni = 0; ni < 2; ni++) acc[mi][ni] = f32x4{0.f, 0.f, 0.f, 0.f};

  for (int ph = 0; ph < 2; ph++) {
    const bf16_t* Ab; const bf16_t* Wb; int lda_, ldw_, K_;
    if (ph == 0) { Ab = xp;            lda_ = Kx; K_ = Kx; Wb = Wih; ldw_ = Kx; }
    else         { Ab = hbase + hoff;  lda_ = Hm; K_ = Hm; Wb = Whh; ldw_ = Hm; }

    const bf16_t* Arow = Ab + (size_t)(m0 + srow) * lda_ + schunk;
    const bf16_t* Wrow = Wb + (size_t)(g * Hm + j0 + jr) * ldw_ + wchunk;
    const int nI = K_ >> 5;

    bf16x8 av  = *(const bf16x8*)(Arow);
    bf16x8 wv0 = *(const bf16x8*)(Wrow);
    bf16x8 wv1 = *(const bf16x8*)(Wrow + 8);
    *(bf16x8*)(AlB[0] + srow * LDSK + schunk) = av;
    *(bf16x8*)(WlB[0] + wrow * LDSK + wchunk) = wv0;
    *(bf16x8*)(WlB[0] + wrow * LDSK + wchunk + 8) = wv1;

    for (int i = 0; i < nI; i++) {
      const int cur = i & 1;
      const bool more = (i + 1 < nI);
      if (more) {
        av  = *(const bf16x8*)(Arow + (i + 1) * 32);
        wv0 = *(const bf16x8*)(Wrow + (i + 1) * 32);
        wv1 = *(const bf16x8*)(Wrow + (i + 1) * 32 + 8);
      }
      __syncthreads();
      if (more) {
        *(bf16x8*)(AlB[cur ^ 1] + srow * LDSK + schunk) = av;
        *(bf16x8*)(WlB[cur ^ 1] + wrow * LDSK + wchunk) = wv0;
        *(bf16x8*)(WlB[cur ^ 1] + wrow * LDSK + wchunk + 8) = wv1;
      }
      bf16x8 afr[4], bfr[2];
      #pragma unroll
      for (int mi = 0; mi < 4; mi++)
        afr[mi] = *(const bf16x8*)(AlB[cur] + (mi * 16 + lrow) * LDSK + quad * 8);
      #pragma unroll
      for (int ni = 0; ni < 2; ni++)
        bfr[ni] = *(const bf16x8*)(WlB[cur] + (wave * 32 + ni * 16 + lrow) * LDSK + quad * 8);
      #pragma unroll
      for (int mi = 0; mi < 4; mi++)
        #pragma unroll
        for (int ni = 0; ni < 2; ni++)
          acc[mi][ni] = MFMA16(afr[mi], bfr[ni], acc[mi][ni]);
    }
    __syncthreads();   // buffers free before next phase / Gx overlay
  }

  #pragma unroll
  for (int mi = 0; mi < 4; mi++)
    #pragma unroll
    for (int ni = 0; ni < 2; ni++) {
      int col = ni * 16 + lrow;
      float bv = p.BSUM[boff + wave * Hm + j0 + col];
      #pragma unroll
      for (int r = 0; r < 4; r++) {
        Gx[wave][mi * 16 + quad * 4 + r][col] = acc[mi][ni][r] + bv;
      }
    }
  __syncthreads();

  float* cbuf = p.CBUF + hoff;
  int m = tid >> 2, jb = (tid & 3) * 8;
  #pragma unroll
  for (int i = 0; i < 8; i++) {
    int j = jb + i;
    float gi = Gx[0][m][j], gf = Gx[1][m][j], gg = Gx[2][m][j], go = Gx[3][m][j];
    size_t off = (size_t)(m0 + m) * Hm + (j0 + j);
    float c_old = cbuf[off];
    float c2 = sigmoidf_(gf) * c_old + sigmoidf_(gi) * tanhf_(gg);
    float h2 = sigmoidf_(go) * tanhf_(c2);
    cbuf[off] = c2;
    houtb[hoff + off] = (bf16_t)h2;
    size_t cs = (size_t)(m0 + m) * 1024 + oldbase + (j0 + j);
    cstar[cs] = (bf16_t)c_old;
    cstar[cs + 512] = (bf16_t)c2;
  }
  __syncthreads();
}

// ---- generic 64x64 lin tile: C = act(A @ W^T + b). Double-buffered LDS.
__device__ __forceinline__ void lin_body(
    const bf16_t* __restrict__ A, int lda,
    const bf16_t* __restrict__ W, int ldw,
    const float* __restrict__ bias,
    bf16_t* Cb, float* Cf, int ldc, int K, int act,
    int m0, int n0, char* SM)
{
  bf16_t* AlB[2] = { (bf16_t*)SM,            (bf16_t*)(SM + 5120) };
  bf16_t* WlB[2] = { (bf16_t*)(SM + 10240),  (bf16_t*)(SM + 15360) };
  const int tid = threadIdx.x;
  const int wave = tid >> 6, lane = tid & 63;
  const int wm = (wave >> 1) * 32, wn = (wave & 1) * 32;
  const int lrow = lane & 15, quad = lane >> 4;
  const int srow = tid >> 2, schunk = (tid & 3) * 8;

  f32x4 acc[2][2];
  #pragma unroll
  for (int mi = 0; mi < 2; mi++)
    #pragma unroll
    for (int ni = 0; ni < 2; ni++) acc[mi][ni] = f32x4{0.f, 0.f, 0.f, 0.f};

  const bf16_t* Arow = A + (size_t)(m0 + srow) * lda + schunk;
  const bf16_t* Wrow = W + (size_t)(n0 + srow) * ldw + schunk;
  const int nI = K >> 5;

  bf16x8 av = *(const bf16x8*)(Arow);
  bf16x8 wv = *(const bf16x8*)(Wrow);
  *(bf16x8*)(AlB[0] + srow * LDSK + schunk) = av;
  *(bf16x8*)(WlB[0] + srow * LDSK + schunk) = wv;

  for (int i = 0; i < nI; i++) {
    const int cur = i & 1;
    const bool more = (i + 1 < nI);
    if (more) {
      av = *(const bf16x8*)(Arow + (i + 1) * 32);
      wv = *(const bf16x8*)(Wrow + (i + 1) * 32);
    }
    __syncthreads();
    if (more) {
      *(bf16x8*)(AlB[cur ^ 1] + srow * LDSK + schunk) = av;
      *(bf16x8*)(WlB[cur ^ 1] + srow * LDSK + schunk) = wv;
    }
    bf16x8 a0 = *(const bf16x8*)(AlB[cur] + (wm + lrow) * LDSK + quad * 8);
    bf16x8 a1 = *(const bf16x8*)(AlB[cur] + (wm + 16 + lrow) * LDSK + quad * 8);
    bf16x8 b0 = *(const bf16x8*)(WlB[cur] + (wn + lrow) * LDSK + quad * 8);
    bf16x8 b1 = *(const bf16x8*)(WlB[cur] + (wn + 16 + lrow) * LDSK + quad * 8);
    acc[0][0] = MFMA16(a0, b0, acc[0][0]);
    acc[0][1] = MFMA16(a0, b1, acc[0][1]);
    acc[1][0] = MFMA16(a1, b0, acc[1][0]);
    acc[1][1] = MFMA16(a1, b1, acc[1][1]);
  }
  __syncthreads();   // buffers free for next body

  #pragma unroll
  for (int mi = 0; mi < 2; mi++)
    #pragma unroll
    for (int ni = 0; ni < 2; ni++) {
      int row0 = m0 + wm + mi * 16 + quad * 4;
      int col = n0 + wn + ni * 16 + lrow;
      float bv = bias[col];
      #pragma unroll
      for (int r = 0; r < 4; r++) {
        float v = acc[mi][ni][r] + bv;
        if (act == 1) v = fmaxf(v, 0.f);
        size_t off = (size_t)(row0 + r) * ldc + col;
        if (Cb) Cb[off] = (bf16_t)v;
        if (Cf) Cf[off] = v;
      }
    }
}

// ---- softmax over 1024 + attended (job = row n)
__device__ __forceinline__ void softmax_body(const PArgs& p, int n, char* SM,
                                             const bf16_t* cstar) {
  float* red = (float*)SM;
  const int tid = threadIdx.x;
  float4 v = *(const float4*)(p.LOGB + (size_t)n * 1024 + tid * 4);
  float mx = fmaxf(fmaxf(v.x, v.y), fmaxf(v.z, v.w));
  red[tid] = mx; __syncthreads();
  for (int s = 128; s > 0; s >>= 1) {
    if (tid < s) red[tid] = fmaxf(red[tid], red[tid + s]);
    __syncthreads();
  }
  mx = red[0]; __syncthreads();
  float e0 = __expf(v.x - mx), e1 = __expf(v.y - mx);
  float e2 = __expf(v.z - mx), e3 = __expf(v.w - mx);
  red[tid] = e0 + e1 + e2 + e3; __syncthreads();
  for (int s = 128; s > 0; s >>= 1) {
    if (tid < s) red[tid] += red[tid + s];
    __syncthreads();
  }
  float inv = 1.0f / red[0];
  bf16x4 c4 = *(const bf16x4*)(cstar + (size_t)n * 1024 + tid * 4);
  bf16x4 o;
  o[0] = (bf16_t)(e0 * inv * (float)c4[0]);
  o[1] = (bf16_t)(e1 * inv * (float)c4[1]);
  o[2] = (bf16_t)(e2 * inv * (float)c4[2]);
  o[3] = (bf16_t)(e3 * inv * (float)c4[3]);
  *(bf16x4*)(p.ATTD + (size_t)n * 1024 + tid * 4) = o;
  __syncthreads();
}

// ---- merged z2|zg1|zg2 (job: m=job&7, ny=job>>3). Double-buffered.
__device__ __forceinline__ void z3_body(const PArgs& p, int job, char* SM) {
  bf16_t* AlB[2] = { (bf16_t*)SM,            (bf16_t*)(SM + 5120) };
  bf16_t* WlB[2] = { (bf16_t*)(SM + 10240),  (bf16_t*)(SM + 15360) };
  const int tid = threadIdx.x;
  const int m0 = (job & 7) * 64, n0 = (job >> 3) * 64;
  const int wave = tid >> 6, lane = tid & 63;
  const int wm = (wave >> 1) * 32, wn = (wave & 1) * 32;
  const int lrow = lane & 15, quad = lane >> 4;
  const int srow = tid >> 2, schunk = (tid & 3) * 8;

  const bf16_t* W; const float* b; int K, nloc;
  if (n0 < 512)       { W = p.POOL + OFF_ATT2W1; b = p.att2_b1; K = 1024; nloc = n0; }
  else if (n0 < 1024) { W = p.POOL + OFF_G1W1;  b = p.g1_b1;  K = 1280; nloc = n0 - 512; }
  else                { W = p.POOL + OFF_G2W1;  b = p.g2_b1;  K = 1280; nloc = n0 - 1024; }

  f32x4 acc[2][2];
  #pragma unroll
  for (int mi = 0; mi < 2; mi++)
    #pragma unroll
    for (int ni = 0; ni < 2; ni++) acc[mi][ni] = f32x4{0.f, 0.f, 0.f, 0.f};

  const bf16_t* Aatt = p.ATTD + (size_t)(m0 + srow) * 1024 + schunk;
  const bf16_t* Amem = p.MEMBF + (size_t)(m0 + srow) * 256 + schunk;
  const bf16_t* Wrow = W + (size_t)(nloc + srow) * K + schunk;
  const int nI = K >> 5;

  bf16x8 av = *(const bf16x8*)(Aatt);
  bf16x8 wv = *(const bf16x8*)(Wrow);
  *(bf16x8*)(AlB[0] + srow * LDSK + schunk) = av;
  *(bf16x8*)(WlB[0] + srow * LDSK + schunk) = wv;

  for (int i = 0; i < nI; i++) {
    const int cur = i & 1;
    const bool more = (i + 1 < nI);
    if (more) {
      int kn = (i + 1) * 32;
      av = (kn < 1024) ? *(const bf16x8*)(Aatt + kn)
                       : *(const bf16x8*)(Amem + (kn - 1024));
      wv = *(const bf16x8*)(Wrow + kn);
    }
    __syncthreads();
    if (more) {
      *(bf16x8*)(AlB[cur ^ 1] + srow * LDSK + schunk) = av;
      *(bf16x8*)(WlB[cur ^ 1] + srow * LDSK + schunk) = wv;
    }
    bf16x8 a0 = *(const bf16x8*)(AlB[cur] + (wm + lrow) * LDSK + quad * 8);
    bf16x8 a1 = *(const bf16x8*)(AlB[cur] + (wm + 16 + lrow) * LDSK + quad * 8);
    bf16x8 b0 = *(const bf16x8*)(WlB[cur] + (wn + lrow) * LDSK + quad * 8);
    bf16x8 b1 = *(const bf16x8*)(WlB[cur] + (wn + 16 + lrow) * LDSK + quad * 8);
    acc[0][0] = MFMA16(a0, b0, acc[0][0]);
    acc[0][1] = MFMA16(a0, b1, acc[0][1]);
    acc[1][0] = MFMA16(a1, b0, acc[1][0]);
    acc[1][1] = MFMA16(a1, b1, acc[1][1]);
  }
  __syncthreads();

  #pragma unroll
  for (int mi = 0; mi < 2; mi++)
    #pragma unroll
    for (int ni = 0; ni < 2; ni++) {
      int row0 = m0 + wm + mi * 16 + quad * 4;
      int cloc = wn + ni * 16 + lrow;
      float bv = b[nloc + cloc];
      #pragma unroll
      for (int r = 0; r < 4; r++) {
        float v = fmaxf(acc[mi][ni][r] + bv, 0.f);
        p.Z3[(size_t)(row0 + r) * 1536 + n0 + cloc] = (bf16_t)v;
      }
    }
}

// ---- cHat/gamma1/gamma2 GEMMs + mem update (single-buffered, 3-way)
__device__ __forceinline__ void gmem_body(const PArgs& p, int job, char* SM) {
  const int tid = threadIdx.x;
  const int m0 = (job & 7) * 64, n0 = (job >> 3) * 64;
  const int wave = tid >> 6, lane = tid & 63;
  const int wm = (wave >> 1) * 32, wn = (wave & 1) * 32;
  const int lrow = lane & 15, quad = lane >> 4;
  const int srow = tid >> 2, schunk = (tid & 3) * 8;

  const bf16_t* Ws[3] = { p.POOL + OFF_ATT2W2, p.POOL + OFF_G1W2, p.POOL + OFF_G2W2 };

  f32x4 acc[3][2][2];
  #pragma unroll
  for (int s = 0; s < 3; s++)
    #pragma unroll
    for (int mi = 0; mi < 2; mi++)
      #pragma unroll
      for (int ni = 0; ni < 2; ni++) acc[s][mi][ni] = f32x4{0.f, 0.f, 0.f, 0.f};

  const bf16_t* Arow = p.Z3 + (size_t)(m0 + srow) * 1536 + schunk;
  bf16x8 avv[3], wvv[3];
  #pragma unroll
  for (int s = 0; s < 3; s++) {
    avv[s] = *(const bf16x8*)(Arow + s * 512);
    wvv[s] = *(const bf16x8*)(Ws[s] + (size_t)(n0 + srow) * 512 + schunk);
  }

  for (int k0 = 0; k0 < 512; k0 += 32) {
    #pragma unroll
    for (int s = 0; s < 3; s++) {
      bf16_t* Az = (bf16_t*)(SM + s * 5120);
      bf16_t* Wz = (bf16_t*)(SM + 15360 + s * 5120);
      *(bf16x8*)(Az + srow * LDSK + schunk) = avv[s];
      *(bf16x8*)(Wz + srow * LDSK + schunk) = wvv[s];
    }
    __syncthreads();
    if (k0 + 32 < 512) {
      #pragma unroll
      for (int s = 0; s < 3; s++) {
        avv[s] = *(const bf16x8*)(Arow + s * 512 + k0 + 32);
        wvv[s] = *(const bf16x8*)(Ws[s] + (size_t)(n0 + srow) * 512 + k0 + 32 + schunk);
      }
    }
    #pragma unroll
    for (int s = 0; s < 3; s++) {
      bf16_t* Az = (bf16_t*)(SM + s * 5120);
      bf16_t* Wz = (bf16_t*)(SM + 15360 + s * 5120);
      bf16x8 a0 = *(const bf16x8*)(Az + (wm + lrow) * LDSK + quad * 8);
      bf16x8 a1 = *(const bf16x8*)(Az + (wm + 16 + lrow) * LDSK + quad * 8);
      bf16x8 b0 = *(const bf16x8*)(Wz + (wn + lrow) * LDSK + quad * 8);
      bf16x8 b1 = *(const bf16x8*)(Wz + (wn + 16 + lrow) * LDSK + quad * 8);
      acc[s][0][0] = MFMA16(a0, b0, acc[s][0][0]);
      acc[s][0][1] = MFMA16(a0, b1, acc[s][0][1]);
      acc[s][1][0] = MFMA16(a1, b0, acc[s][1][0]);
      acc[s][1][1] = MFMA16(a1, b1, acc[s][1][1]);
    }
    __syncthreads();
  }
  #pragma unroll
  for (int mi = 0; mi < 2; mi++)
    #pragma unroll
    for (int ni = 0; ni < 2; ni++) {
      int row0 = m0 + wm + mi * 16 + quad * 4;
      int col = n0 + wn + ni * 16 + lrow;
      float bC = p.att2_b2[col], b1v = p.g1_b2[col], b2v = p.g2_b2[col];
      #pragma unroll
      for (int r = 0; r < 4; r++) {
        float cHat = tanhf_(acc[0][mi][ni][r] + bC);
        float g1 = sigmoidf_(acc[1][mi][ni][r] + b1v);
        float g2 = sigmoidf_(acc[2][mi][ni][r] + b2v);
        size_t off = (size_t)(row0 + r) * 256 + col;
        float nm = g1 * p.MEMF[off] + g2 * cHat;
        p.MEMF[off] = nm;
        p.MEMBF[off] = (bf16_t)nm;
      }
    }
}

// ---- partial max (job in [0,48))
__device__ __forceinline__ void maxpart_body(const PArgs& p, int job, char* SM) {
  float* red = (float*)SM;
  const int b = job >> 4, chunk = job & 15;
  const int tid = threadIdx.x;
  float mx = -3.4e38f;
  for (int i = tid; i < 32 * 128; i += 256) {
    int n = chunk * 32 + (i >> 7), j = i & 127;
    mx = fmaxf(mx, p.PL[(size_t)n * 384 + b * 128 + j]);
  }
  red[tid] = mx; __syncthreads();
  for (int s = 128; s > 0; s >>= 1) {
    if (tid < s) red[tid] = fmaxf(red[tid], red[tid + s]);
    __syncthreads();
  }
  if (tid == 0) p.MAXP[job] = red[0];
  __syncthreads();
}

// ---- final output row (job = row n)
__device__ __forceinline__ void out_body(const PArgs& p, int n, char* SM) {
  float* hs  = (float*)SM;
  float* red = (float*)(SM + 1536);
  float* Ms  = (float*)(SM + 2560);
  const int tid = threadIdx.x;
  if (tid < 3) {
    float m = -3.4e38f;
    #pragma unroll
    for (int i = 0; i < 16; i++) m = fmaxf(m, p.MAXP[tid * 16 + i]);
    Ms[tid] = m;
  }
  __syncthreads();
  const float M0 = Ms[0], M1 = Ms[1], M2 = Ms[2];
  for (int idx = tid; idx < 384; idx += 256) {
    float v;
    if (idx < 128) {
      float d0 = p.PL[(size_t)n * 384 + idx] - M0;
      float d1 = p.PL[(size_t)n * 384 + 128 + idx] - M1;
      float d2 = p.PL[(size_t)n * 384 + 256 + idx] - M2;
      v = __expf(d0) * d0 + __expf(d1) * d1 + __expf(d2) * d2;
    } else {
      v = p.MEMF[(size_t)n * 256 + idx - 128];
    }
    hs[idx] = v;
  }
  __syncthreads();
  float acc = p.o_b1[tid];
  const float* wr = p.o_w1 + (size_t)tid * 384;
  #pragma unroll 4
  for (int k = 0; k < 384; k += 4) {
    float4 w = *(const float4*)(wr + k);
    acc += w.x * hs[k] + w.y * hs[k + 1] + w.z * hs[k + 2] + w.w * hs[k + 3];
  }
  red[tid] = fmaxf(acc, 0.f) * p.o_w2[tid];
  __syncthreads();
  for (int s = 128; s > 0; s >>= 1) {
    if (tid < s) red[tid] += red[tid + s];
    __syncthreads();
  }
  if (tid == 0) p.out[n] = red[0] + p.o_b2[0];
  __syncthreads();
}

// -------- attention chain for one step (attn team, 24 blocks of one XCD)
__device__ __forceinline__ void attn_chain(const PArgs& p, int g, int rb,
                                           const bf16_t* cs_prev, char* SM,
                                           unsigned* teamc, unsigned& tk)
{
  if (rb < 8)
    lin_body(cs_prev, 1024, p.POOL + OFF_ATT1W1, 1024, p.att1_b1,
             p.Z1, (float*)0, 512, 1024, 1, g * 64, rb * 64, SM);
  lbar(teamc, 24u * (++tk));
  if (rb < 16)
    lin_body(p.Z1, 512, p.POOL + OFF_ATT1W2, 512, p.att1_b2,
             (bf16_t*)0, p.LOGB, 1024, 512, 0, g * 64, rb * 64, SM);
  lbar(teamc, 24u * (++tk));
  for (int j = rb; j < 64; j += 24) softmax_body(p, g * 64 + j, SM, cs_prev);
  lbar(teamc, 24u * (++tk));
  z3_body(p, (rb << 3) | g, SM);
  lbar(teamc, 24u * (++tk));
  if (rb < 4) gmem_body(p, (rb << 3) | g, SM);
}

// ============================================================ persistent
__global__ void __launch_bounds__(256) persist_kernel(PArgs p) {
  __shared__ __align__(16) char SM[34816];
  __shared__ int meta[12];   // [0]=xcd, [1]=rank, [2..9]=counts, [10]=poison
  const int bid = blockIdx.x;
  const int tid = threadIdx.x;
  unsigned bk = 0;

  // ---------------- P0: zero state + convert inputs/weights + bias sums
  {
    float4* z = (float4*)p.HB0;
    for (int i = bid * 256 + tid; i < 180224; i += GRIDP * 256)
      z[i] = make_float4(0.f, 0.f, 0.f, 0.f);

    int gid = bid * 256 + tid;
    if (gid < 1024)      p.BSUM[gid] = p.bih_l[gid] + p.bhh_l[gid];
    else if (gid < 1536) p.BSUM[gid] = p.bih_a[gid - 1024] + p.bhh_a[gid - 1024];
    else if (gid < 2048) p.BSUM[gid] = p.bih_v[gid - 1536] + p.bhh_v[gid - 1536];

    for (int r = bid; r < TSTEPS * NB; r += GRIDP) {
      const float4* xr = (const float4*)(p.x + (size_t)r * DIN);
      int q = tid;
      if (q < 144) {
        float4 v; bf16_t* dst;
        if (q < 80) {
          v = (q < 75) ? xr[q] : make_float4(0.f, 0.f, 0.f, 0.f);
          dst = p.XL + (size_t)r * 320 + q * 4;
        } else if (q < 112) {
          v = xr[75 + (q - 80)];
          dst = p.XA + (size_t)r * 128 + (q - 80) * 4;
        } else {
          v = xr[107 + (q - 112)];
          dst = p.XV + (size_t)r * 128 + (q - 112) * 4;
        }
        bf16x4 o;
        o[0] = (bf16_t)v.x; o[1] = (bf16_t)v.y; o[2] = (bf16_t)v.z; o[3] = (bf16_t)v.w;
        *(bf16x4*)dst = o;
      }
    }

    for (int m = 0; m < 17; m++) {
      const float* src = p.cvt_src[m];
      bf16_t* dst = p.POOL + p.cvt_dst[m];
      int K = p.cvt_K[m], Kp = p.cvt_Kpad[m], R = p.cvt_rows[m];
      int Kq = Kp >> 2, Ksq = K >> 2;
      for (int r = bid; r < R; r += GRIDP) {
        const float4* sr = (const float4*)(src + (size_t)r * K);
        for (int q = tid; q < Kq; q += 256) {
          float4 v = (q < Ksq) ? sr[q] : make_float4(0.f, 0.f, 0.f, 0.f);
          bf16x4 o;
          o[0] = (bf16_t)v.x; o[1] = (bf16_t)v.y; o[2] = (bf16_t)v.z; o[3] = (bf16_t)v.w;
          *(bf16x4*)(dst + (size_t)r * Kp + q * 4) = o;
        }
      }
    }

    if (tid == 0) {
      unsigned raw = __builtin_amdgcn_s_getreg(HWREG_XCC_ID);
      if (raw > 7u) {
        __hip_atomic_store(p.BAR + 159, 1u, __ATOMIC_RELAXED, __HIP_MEMORY_SCOPE_AGENT);
        raw &= 7u;
      }
      meta[0] = (int)raw;
      meta[1] = (int)__hip_atomic_fetch_add(p.BAR + 160 + raw * 16, 1u,
                    __ATOMIC_RELAXED, __HIP_MEMORY_SCOPE_AGENT);
    }
  }
  gbar(p.BAR, bk++, bid);

  // census
  if (tid < 8)
    meta[2 + tid] = (int)__hip_atomic_load(p.BAR + 160 + tid * 16,
                        __ATOMIC_RELAXED, __HIP_MEMORY_SCOPE_AGENT);
  if (tid == 8)
    meta[10] = (int)__hip_atomic_load(p.BAR + 159,
                   __ATOMIC_RELAXED, __HIP_MEMORY_SCOPE_AGENT);
  __syncthreads();
  bool teammode = (meta[10] == 0) && (p.allow_team != 0);
  #pragma unroll
  for (int i = 0; i < 8; i++)
    if (meta[2 + i] != 32) teammode = false;

  if (teammode) {
    // ===== per-XCD team split: 8 LSTM blocks (ranks 24..31) run gates(t)
    // ===== while 24 attn blocks (ranks 0..23) run attn(t-1).
    const int g = meta[0];
    const int rank = meta[1];
    unsigned* fullc = p.BAR + 288 + g * 16;
    unsigned* teamc = p.BAR + 416 + g * 16;
    unsigned lk = 0, tk = 0;
    const int ra = rank - 24;   // >=0 -> LSTM team
    const int rb = rank;        // <24 -> attn team

    for (int t = 0; t < TSTEPS; t++) {
      lbar(fullc, 32u * (++lk));   // publishes gates(t-1) + gmem(t-2)
      const bf16_t* hin = (t & 1) ? p.HB1 : p.HB0;
      bf16_t* hout      = (t & 1) ? p.HB0 : p.HB1;
      bf16_t* cs_cur    = (t & 1) ? p.CSTAR2 : p.CSTAR;
      const bf16_t* cs_prev = (t & 1) ? p.CSTAR : p.CSTAR2;
      if (ra >= 0) {
        gates_body(p, g * 16 + ra,     t, SM, hin, hout, cs_cur);
        gates_body(p, g * 16 + 8 + ra, t, SM, hin, hout, cs_cur);
      } else if (t > 0) {
        attn_chain(p, g, rb, cs_prev, SM, teamc, tk);   // attn(t-1)
      }
    }
    lbar(fullc, 32u * (++lk));   // gates(63) published
    if (ra < 0) attn_chain(p, g, rb, p.CSTAR2, SM, teamc, tk);  // attn(63)
  } else {
    // ===== fallback: global barriers every phase (proven path)
    for (int t = 0; t < TSTEPS; t++) {
      const bf16_t* hin = (t & 1) ? p.HB1 : p.HB0;
      bf16_t* hout      = (t & 1) ? p.HB0 : p.HB1;
      for (int job = bid; job < 128; job += GRIDP)
        gates_body(p, job, t, SM, hin, hout, p.CSTAR);
      gbar(p.BAR, bk++, bid);

      for (int job = bid; job < 64; job += GRIDP)
        lin_body(p.CSTAR, 1024, p.POOL + OFF_ATT1W1, 1024, p.att1_b1,
                 p.Z1, (float*)0, 512, 1024, 1, (job & 7) * 64, (job >> 3) * 64, SM);
      gbar(p.BAR, bk++, bid);

      for (int job = bid; job < 128; job += GRIDP)
        lin_body(p.Z1, 512, p.POOL + OFF_ATT1W2, 512, p.att1_b2,
                 (bf16_t*)0, p.LOGB, 1024, 512, 0, (job & 7) * 64, (job >> 3) * 64, SM);
      gbar(p.BAR, bk++, bid);

      for (int job = bid; job < 512; job += GRIDP)
        softmax_body(p, job, SM, p.CSTAR);
      gbar(p.BAR, bk++, bid);

      for (int job = bid; job < 192; job += GRIDP) z3_body(p, job, SM);
      gbar(p.BAR, bk++, bid);

      for (int job = bid; job < 32; job += GRIDP) gmem_body(p, job, SM);
      gbar(p.BAR, bk++, bid);
    }
  }
  gbar(p.BAR, bk++, bid);   // cross-XCD: publish h, MEMF

  // ---------------- tail: PL GEMMs -> partial max -> output MLP
  for (int job = bid; job < 48; job += GRIDP) {
    int mat = job >> 4, rem = job & 15;
    int m0 = (rem & 7) * 64, n0 = (rem >> 3) * 64;
    const bf16_t* h = (mat == 0) ? p.HB0 : (mat == 1) ? p.HB0 + 131072 : p.HB0 + 196608;
    int lda = (mat == 0) ? 256 : 128;
    const bf16_t* W = p.POOL + ((mat == 0) ? OFF_FLW : (mat == 1) ? OFF_FAW : OFF_FVW);
    const float* b = (mat == 0) ? p.fl_b : (mat == 1) ? p.fa_b : p.fv_b;
    lin_body(h, lda, W, lda, b, (bf16_t*)0, p.PL + mat * 128, 384, lda, 0, m0, n0, SM);
  }
  gbar(p.BAR, bk++, bid);

  for (int job = bid; job < 48; job += GRIDP) maxpart_body(p, job, SM);
  gbar(p.BAR, bk++, bid);

  for (int job = bid; job < 512; job += GRIDP) out_body(p, job, SM);
}

// ============================================================ fallback path
// (used only if the cooperative launch is rejected)

__global__ __launch_bounds__(256) void zero_kernel(float4* p, int n4) {
  int i = blockIdx.x * 256 + threadIdx.x;
  if (i < n4) p[i] = make_float4(0.f, 0.f, 0.f, 0.f);
}

__global__ __launch_bounds__(256) void cvt_pad_kernel(
    const float* __restrict__ src, bf16_t* __restrict__ dst, int K, int Kpad)
{
  int r = blockIdx.x;
  for (int k = threadIdx.x; k < Kpad; k += 256)
    dst[(size_t)r * Kpad + k] = (k < K) ? (bf16_t)src[(size_t)r * K + k] : (bf16_t)0.f;
}

__global__ __launch_bounds__(256) void cvt_x_kernel(
    const float* __restrict__ x, bf16_t* __restrict__ xl,
    bf16_t* __restrict__ xa, bf16_t* __restrict__ xv)
{
  int r = blockIdx.x;
  const float* xr = x + (size_t)r * DIN;
  for (int c = threadIdx.x; c < 576; c += 256) {
    if (c < 320) {
      xl[(size_t)r * 320 + c] = (c < 300) ? (bf16_t)xr[c] : (bf16_t)0.f;
    } else if (c < 448) {
      xa[(size_t)r * 128 + (c - 320)] = (bf16_t)xr[300 + (c - 320)];
    } else {
      xv[(size_t)r * 128 + (c - 448)] = (bf16_t)xr[428 + (c - 448)];
    }
  }
}

__global__ __launch_bounds__(256) void bias_sum_kernel(
    const float* __restrict__ bih_l, const float* __restrict__ bhh_l,
    const float* __restrict__ bih_a, const float* __restrict__ bhh_a,
    const float* __restrict__ bih_v, const float* __restrict__ bhh_v,
    float* __restrict__ bsum)
{
  int i = blockIdx.x * 256 + threadIdx.x;
  if (i < 1024)      bsum[i] = bih_l[i] + bhh_l[i];
  else if (i < 1536) bsum[i] = bih_a[i - 1024] + bhh_a[i - 1024];
  else if (i < 2048) bsum[i] = bih_v[i - 1536] + bhh_v[i - 1536];
}

__global__ __launch_bounds__(256) void gates_cell_kernel_fb(PArgs p, int t) {
  __shared__ __align__(16) char SM[34816];
  const bf16_t* hin = (t & 1) ? p.HB1 : p.HB0;
  bf16_t* hout      = (t & 1) ? p.HB0 : p.HB1;
  gates_body(p, blockIdx.x * 16 + blockIdx.y, t, SM, hin, hout, p.CSTAR);
}

__global__ __launch_bounds__(256) void mfma_lin_kernel_fb(
    const bf16_t* A, int lda, const bf16_t* W, int ldw,
    const float* bias, bf16_t* Cb, float* Cf, int ldc, int K, int act)
{
  __shared__ __align__(16) char SM[20480];
  lin_body(A, lda, W, ldw, bias, Cb, Cf, ldc, K, act,
           blockIdx.x * 64, blockIdx.y * 64, SM);
}

__global__ __launch_bounds__(256) void softmax_attend_kernel_fb(PArgs p) {
  __shared__ __align__(16) char SM[1024];
  softmax_body(p, blockIdx.x, SM, p.CSTAR);
}

__global__ __launch_bounds__(256) void z3_kernel_fb(PArgs p) {
  __shared__ __align__(16) char SM[20480];
  z3_body(p, blockIdx.x + blockIdx.y * 8, SM);
}

__global__ __launch_bounds__(256) void gmem_kernel_fb(PArgs p) {
  __shared__ __align__(16) char SM[30720];
  gmem_body(p, blockIdx.x + blockIdx.y * 8, SM);
}

__global__ __launch_bounds__(256) void maxpart_kernel_fb(PArgs p) {
  __shared__ __align__(16) char SM[1024];
  maxpart_body(p, blockIdx.x, SM);
}

__global__ __launch_bounds__(256) void out_kernel_fb(PArgs p) {
  __shared__ __align__(16) char SM[2576];
  out_body(p, blockIdx.x, SM);
}

// ============================================================ host launcher
extern "C" void kernel_launch(void* const* d_in, const int* in_sizes, int n_in,
                              void* d_out, int out_size, void* d_ws, size_t ws_size,
                              hipStream_t stream)
{
  const float* x      = (const float*)d_in[0];
  const float* Wih_l  = (const float*)d_in[1];
  const float* Whh_l  = (const float*)d_in[2];
  const float* bih_l  = (const float*)d_in[3];
  const float* bhh_l  = (const float*)d_in[4];
  const float* Wih_a  = (const float*)d_in[5];
  const float* Whh_a  = (const float*)d_in[6];
  const float* bih_a  = (const float*)d_in[7];
  const float* bhh_a  = (const float*)d_in[8];
  const float* Wih_v  = (const float*)d_in[9];
  const float* Whh_v  = (const float*)d_in[10];
  const float* bih_v  = (const float*)d_in[11];
  const float* bhh_v  = (const float*)d_in[12];
  const float* att1_w1 = (const float*)d_in[13];
  const float* att1_b1 = (const float*)d_in[14];
  const float* att1_w2 = (const float*)d_in[15];
  const float* att1_b2 = (const float*)d_in[16];
  const float* att2_w1 = (const float*)d_in[17];
  const float* att2_b1 = (const float*)d_in[18];
  const float* att2_w2 = (const float*)d_in[19];
  const float* att2_b2 = (const float*)d_in[20];
  const float* g1_w1  = (const float*)d_in[21];
  const float* g1_b1  = (const float*)d_in[22];
  const float* g1_w2  = (const float*)d_in[23];
  const float* g1_b2  = (const float*)d_in[24];
  const float* g2_w1  = (const float*)d_in[25];
  const float* g2_b1  = (const float*)d_in[26];
  const float* g2_w2  = (const float*)d_in[27];
  const float* g2_b2  = (const float*)d_in[28];
  const float* fl_w   = (const float*)d_in[29];
  const float* fl_b   = (const float*)d_in[30];
  const float* fa_w   = (const float*)d_in[31];
  const float* fa_b   = (const float*)d_in[32];
  const float* fv_w   = (const float*)d_in[33];
  const float* fv_b   = (const float*)d_in[34];
  const float* o_w1   = (const float*)d_in[35];
  const float* o_b1   = (const float*)d_in[36];
  const float* o_w2   = (const float*)d_in[37];
  const float* o_b2   = (const float*)d_in[38];

  char* base = (char*)d_ws;
  PArgs pa;
  pa.x = x;
  pa.bih_l = bih_l; pa.bhh_l = bhh_l;
  pa.bih_a = bih_a; pa.bhh_a = bhh_a;
  pa.bih_v = bih_v; pa.bhh_v = bhh_v;
  pa.att1_b1 = att1_b1; pa.att1_b2 = att1_b2;
  pa.att2_b1 = att2_b1; pa.att2_b2 = att2_b2;
  pa.g1_b1 = g1_b1; pa.g1_b2 = g1_b2;
  pa.g2_b1 = g2_b1; pa.g2_b2 = g2_b2;
  pa.fl_b = fl_b; pa.fa_b = fa_b; pa.fv_b = fv_b;
  pa.o_w1 = o_w1; pa.o_b1 = o_b1; pa.o_w2 = o_w2; pa.o_b2 = o_b2;

  const float* csrc[17] = { Wih_l, Whh_l, Wih_a, Whh_a, Wih_v, Whh_v,
                            att1_w1, att1_w2, att2_w1, att2_w2,
                            g1_w1, g1_w2, g2_w1, g2_w2, fl_w, fa_w, fv_w };
  const unsigned cdst[17] = { OFF_WIHP_L, OFF_WHH_L, OFF_WIHP_A, OFF_WHH_A,
                              OFF_WIHP_V, OFF_WHH_V, OFF_ATT1W1, OFF_ATT1W2,
                              OFF_ATT2W1, OFF_ATT2W2, OFF_G1W1, OFF_G1W2,
                              OFF_G2W1, OFF_G2W2, OFF_FLW, OFF_FAW, OFF_FVW };
  const int cK[17]   = { 300, 256, 128, 128, 128, 128, 1024, 512, 1024, 512,
                         1280, 512, 1280, 512, 256, 128, 128 };
  const int cKp[17]  = { 320, 256, 128, 128, 128, 128, 1024, 512, 1024, 512,
                         1280, 512, 1280, 512, 256, 128, 128 };
  const int cR[17]   = { 1024, 1024, 512, 512, 512, 512, 512, 1024, 512, 256,
                         512, 256, 512, 256, 128, 128, 128 };
  for (int i = 0; i < 17; i++) {
    pa.cvt_src[i] = csrc[i]; pa.cvt_dst[i] = cdst[i];
    pa.cvt_K[i] = cK[i]; pa.cvt_Kpad[i] = cKp[i]; pa.cvt_rows[i] = cR[i];
  }

  pa.POOL   = (bf16_t*)(base);
  pa.XL     = (bf16_t*)(base + 8388608);
  pa.XA     = (bf16_t*)(base + 29360128);
  pa.XV     = (bf16_t*)(base + 37748736);
  pa.HB0    = (bf16_t*)(base + 46137344);
  pa.HB1    = (bf16_t*)(base + 46661632);
  pa.CBUF   = (float*) (base + 47185920);
  pa.MEMF   = (float*) (base + 48234496);
  pa.MEMBF  = (bf16_t*)(base + 48758784);
  pa.CSTAR  = (bf16_t*)(base + 49020928);
  pa.Z1     = (bf16_t*)(base + 50069504);
  pa.LOGB   = (float*) (base + 50593792);
  pa.ATTD   = (bf16_t*)(base + 52690944);
  pa.Z3     = (bf16_t*)(base + 53739520);
  pa.PL     = (float*) (base + 55312384);
  pa.MAXP   = (float*) (base + 56098816);
  pa.BSUM   = (float*) (base + 56099072);
  pa.BAR    = (unsigned*)(base + 56107264);  // 4 KiB
  pa.CSTAR2 = (bf16_t*)(base + 56111616);    // 1 MiB, ends 57160192
  pa.out    = (float*)d_out;
  pa.allow_team = (ws_size >= 57160192u) ? 1 : 0;

  // barrier/census counters must be zero at kernel start (each run)
  hipMemsetAsync(pa.BAR, 0, 4096, stream);

  void* kargs[] = { (void*)&pa };
  hipError_t e = hipLaunchCooperativeKernel((const void*)persist_kernel,
                                            dim3(GRIDP), dim3(256), kargs, 0, stream);
  if (e == hipSuccess) return;

  // ---------------- fallback: original multi-kernel schedule
  zero_kernel<<<704, 256, 0, stream>>>((float4*)pa.HB0, 180224);
  cvt_x_kernel<<<TSTEPS * NB, 256, 0, stream>>>(x, pa.XL, pa.XA, pa.XV);
  for (int i = 0; i < 17; i++)
    cvt_pad_kernel<<<cR[i], 256, 0, stream>>>(csrc[i], pa.POOL + cdst[i], cK[i], cKp[i]);
  bias_sum_kernel<<<8, 256, 0, stream>>>(bih_l, bhh_l, bih_a, bhh_a, bih_v, bhh_v, pa.BSUM);

  for (int t = 0; t < TSTEPS; t++) {
    gates_cell_kernel_fb<<<dim3(8, 16), 256, 0, stream>>>(pa, t);
    mfma_lin_kernel_fb<<<dim3(8, 8), 256, 0, stream>>>(
        pa.CSTAR, 1024, pa.POOL + OFF_ATT1W1, 1024, att1_b1,
        pa.Z1, (float*)nullptr, 512, 1024, 1);
    mfma_lin_kernel_fb<<<dim3(8, 16), 256, 0, stream>>>(
        pa.Z1, 512, pa.POOL + OFF_ATT1W2, 512, att1_b2,
        (bf16_t*)nullptr, pa.LOGB, 1024, 512, 0);
    softmax_attend_kernel_fb<<<512, 256, 0, stream>>>(pa);
    z3_kernel_fb<<<dim3(8, 24), 256, 0, stream>>>(pa);
    gmem_kernel_fb<<<dim3(8, 4), 256, 0, stream>>>(pa);
  }

  bf16_t* h_l = pa.HB0;
  bf16_t* h_a = pa.HB0 + 131072;
  bf16_t* h_v = pa.HB0 + 196608;
  mfma_lin_kernel_fb<<<dim3(8, 2), 256, 0, stream>>>(
      h_l, 256, pa.POOL + OFF_FLW, 256, fl_b, (bf16_t*)nullptr, pa.PL, 384, 256, 0);
  mfma_lin_kernel_fb<<<dim3(8, 2), 256, 0, stream>>>(
      h_a, 128, pa.POOL + OFF_FAW, 128, fa_b, (bf16_t*)nullptr, pa.PL + 128, 384, 128, 0);
  mfma_lin_kernel_fb<<<dim3(8, 2), 256, 0, stream>>>(
      h_v, 128, pa.POOL + OFF_FVW, 128, fv_b, (bf16_t*)nullptr, pa.PL + 256, 384, 128, 0);
  maxpart_kernel_fb<<<48, 256, 0, stream>>>(pa);
  out_kernel_fb<<<512, 256, 0, stream>>>(pa);
}